// Round 9
// baseline (22290.622 us; speedup 1.0000x reference)
//
#include <hip/hip_runtime.h>
#include <cstdint>
#include <cstddef>
#include <math.h>

#define A_N   1024
#define OBS_N 2048
#define TD_N  256
#define H_N   128
#define M_N   16
#define AE_N  64
#define NWGC  16   // k_scan grid: 16 WGs (8 parallel steps), 1 WG/CU (LDS-forced)

__device__ __forceinline__ float sigf(float x) { return 1.0f / (1.0f + expf(-x)); }
__device__ __forceinline__ float dot4(float4 a, float4 b) {
  return a.x * b.x + a.y * b.y + a.z * b.z + a.w * b.w;
}

// C may arrive as uint8 (1B/elem) or int32 (4B/elem). Detect on device.
__device__ __forceinline__ bool c_at(const unsigned char* C, int as_int, size_t idx) {
  return as_int ? (((const int*)C)[idx] != 0) : (C[idx] != 0);
}

__global__ __launch_bounds__(64) void k_cdet(const unsigned char* __restrict__ C, int* __restrict__ flag) {
  int lane = threadIdx.x;
  int cnt = 0;
  for (int i = lane; i < 4096; i += 64) cnt += (C[i] != 0) ? 1 : 0;
  for (int off = 32; off; off >>= 1) cnt += __shfl_down(cnt, off);
  if (lane == 0) flag[0] = (cnt < 40) ? 1 : 0;
}

// ---------------- k1: t = relu(LN(obs@W1 + b1)) ----------------
__global__ __launch_bounds__(256) void k_actor1a(const float* __restrict__ obs,
    const float* __restrict__ W1, const float* __restrict__ b1,
    const float* __restrict__ g1, const float* __restrict__ bt1,
    float* __restrict__ tout) {
  __shared__ float S[4 * OBS_N];
  __shared__ float red[4][4][2];
  int tid = threadIdx.x;
  int r0 = blockIdx.x * 4;
  {
    const float4* src = (const float4*)(obs + (size_t)r0 * OBS_N);
    float4* dst = (float4*)S;
    for (int i = tid; i < 4 * OBS_N / 4; i += 256) dst[i] = src[i];
  }
  __syncthreads();
  int j = tid;
  float acc0 = 0, acc1 = 0, acc2 = 0, acc3 = 0;
  const float4* S4 = (const float4*)S;
  for (int k4 = 0; k4 < OBS_N / 4; k4++) {
    float w0 = W1[(k4 * 4 + 0) * TD_N + j];
    float w1 = W1[(k4 * 4 + 1) * TD_N + j];
    float w2 = W1[(k4 * 4 + 2) * TD_N + j];
    float w3 = W1[(k4 * 4 + 3) * TD_N + j];
    float4 s0 = S4[0 * 512 + k4], s1 = S4[1 * 512 + k4], s2 = S4[2 * 512 + k4], s3 = S4[3 * 512 + k4];
    acc0 += s0.x * w0 + s0.y * w1 + s0.z * w2 + s0.w * w3;
    acc1 += s1.x * w0 + s1.y * w1 + s1.z * w2 + s1.w * w3;
    acc2 += s2.x * w0 + s2.y * w1 + s2.z * w2 + s2.w * w3;
    acc3 += s3.x * w0 + s3.y * w1 + s3.z * w2 + s3.w * w3;
  }
  float z[4] = {acc0 + b1[j], acc1 + b1[j], acc2 + b1[j], acc3 + b1[j]};
  int w = tid >> 6, lane = tid & 63;
  for (int r = 0; r < 4; r++) {
    float v = z[r], v2 = z[r] * z[r];
    for (int off = 32; off; off >>= 1) { v += __shfl_down(v, off); v2 += __shfl_down(v2, off); }
    if (lane == 0) { red[r][w][0] = v; red[r][w][1] = v2; }
  }
  __syncthreads();
  for (int r = 0; r < 4; r++) {
    float sm = red[r][0][0] + red[r][1][0] + red[r][2][0] + red[r][3][0];
    float sq = red[r][0][1] + red[r][1][1] + red[r][2][1] + red[r][3][1];
    float mean = sm * (1.0f / TD_N);
    float var = sq * (1.0f / TD_N) - mean * mean;
    float rs = 1.0f / sqrtf(var + 1e-5f);
    float val = (z[r] - mean) * rs * g1[j] + bt1[j];
    tout[(size_t)(r0 + r) * TD_N + j] = fmaxf(val, 0.0f);
  }
}

// ---------------- k2: thoughts = LN(t@W2 + b2) -> thA (= d_out) ----------------
__global__ __launch_bounds__(256) void k_actor1b(const float* __restrict__ tin,
    const float* __restrict__ W2, const float* __restrict__ b2,
    const float* __restrict__ g2, const float* __restrict__ bt2,
    float* __restrict__ th) {
  __shared__ float S[4 * TD_N];
  __shared__ float red[4][4][2];
  int tid = threadIdx.x;
  int r0 = blockIdx.x * 4;
  for (int i = tid; i < 4 * TD_N; i += 256) S[i] = tin[(size_t)r0 * TD_N + i];
  __syncthreads();
  int j = tid;
  float z[4] = {0, 0, 0, 0};
  const float4* S4 = (const float4*)S;
  for (int k4 = 0; k4 < TD_N / 4; k4++) {
    float w0 = W2[(k4 * 4 + 0) * TD_N + j];
    float w1 = W2[(k4 * 4 + 1) * TD_N + j];
    float w2v = W2[(k4 * 4 + 2) * TD_N + j];
    float w3 = W2[(k4 * 4 + 3) * TD_N + j];
#pragma unroll
    for (int r = 0; r < 4; r++) {
      float4 sv = S4[r * 64 + k4];
      z[r] += sv.x * w0 + sv.y * w1 + sv.z * w2v + sv.w * w3;
    }
  }
  for (int r = 0; r < 4; r++) z[r] += b2[j];
  int w = tid >> 6, lane = tid & 63;
  for (int r = 0; r < 4; r++) {
    float v = z[r], v2 = z[r] * z[r];
    for (int off = 32; off; off >>= 1) { v += __shfl_down(v, off); v2 += __shfl_down(v2, off); }
    if (lane == 0) { red[r][w][0] = v; red[r][w][1] = v2; }
  }
  __syncthreads();
  for (int r = 0; r < 4; r++) {
    float sm = red[r][0][0] + red[r][1][0] + red[r][2][0] + red[r][3][0];
    float sq = red[r][0][1] + red[r][1][1] + red[r][2][1] + red[r][3][1];
    float mean = sm * (1.0f / TD_N);
    float var = sq * (1.0f / TD_N) - mean * mean;
    float rs = 1.0f / sqrtf(var + 1e-5f);
    th[(size_t)(r0 + r) * TD_N + j] = (z[r] - mean) * rs * g2[j] + bt2[j];
  }
}

// ---------------- k3: attention unit -> is_init (fp64: x>0 decision is razor-thin) ----------------
__global__ __launch_bounds__(256) void k_att(const float* __restrict__ th,
    const float* __restrict__ aW1, const float* __restrict__ ab1,
    const float* __restrict__ aW2, const float* __restrict__ ab2,
    const float* __restrict__ aW3, const float* __restrict__ ab3,
    int* __restrict__ isin) {
  __shared__ float S[4 * TD_N];
  __shared__ double A1[4 * AE_N];
  __shared__ double A2[4 * AE_N];
  int tid = threadIdx.x;
  int r0 = blockIdx.x * 4;
  for (int i = tid; i < 4 * TD_N; i += 256) S[i] = th[(size_t)r0 * TD_N + i];
  __syncthreads();
  int r = tid >> 6, c = tid & 63;
  double acc = 0;
  for (int k = 0; k < TD_N; k++) acc += (double)S[r * TD_N + k] * (double)aW1[k * AE_N + c];
  acc += (double)ab1[c];
  A1[r * AE_N + c] = acc > 0.0 ? acc : 0.0;
  __syncthreads();
  acc = 0;
  for (int k = 0; k < AE_N; k++) acc += A1[r * AE_N + k] * (double)aW2[k * AE_N + c];
  acc += (double)ab2[c];
  A2[r * AE_N + c] = acc > 0.0 ? acc : 0.0;
  __syncthreads();
  double p = A2[r * AE_N + c] * (double)aW3[c];
  for (int off = 32; off; off >>= 1) p += __shfl_down(p, off);
  if (c == 0) isin[r0 + r] = ((p + (double)ab3[0]) > 0.0) ? 1 : 0;
}

// ---------------- k_memb: member indices (ascending) per row ----------------
__global__ __launch_bounds__(64) void k_memb(const unsigned char* __restrict__ C,
    const int* __restrict__ flag, int* __restrict__ memb) {
  int s = blockIdx.x, lane = threadIdx.x;
  int as_int = flag[0];
  if (lane < M_N) memb[s * M_N + lane] = lane;  // safe defaults (never poison)
  __syncthreads();
  int base = 0;
  for (int ch = 0; ch < 16; ch++) {
    int col = ch * 64 + lane;
    bool v = c_at(C, as_int, (size_t)s * A_N + col);
    unsigned long long m = __ballot(v);
    if (v) {
      int pos = base + __popcll(m & ((1ull << lane) - 1ull));
      if (pos < M_N) memb[s * M_N + pos] = col;
    }
    base += __popcll(m);
  }
}

// ---------------- k_req: write ordinal per (step, member slot) ----------------
__global__ __launch_bounds__(256) void k_req(const unsigned char* __restrict__ C,
    const int* __restrict__ flag, const int* __restrict__ memb,
    const int* __restrict__ isin, int* __restrict__ req) {
  __shared__ int Ls[A_N];
  int s = blockIdx.x, tid = threadIdx.x;
  int as_int = flag[0];
  for (int i = tid; i < A_N; i += 256) Ls[i] = isin[i];
  __syncthreads();
  int i = tid >> 4, sub = tid & 15;
  int m = memb[s * M_N + i] & (A_N - 1);
  int cnt = 0;
  for (int s2 = sub; s2 < s; s2 += 16)
    if (Ls[s2] && c_at(C, as_int, (size_t)s2 * A_N + m)) cnt++;
  for (int off = 1; off < 16; off <<= 1) cnt += __shfl_xor(cnt, off);
  if (sub == 0) req[s * M_N + i] = cnt;
}

// ---------------- k_prep: pair-split weight re-layouts, bias sums, barrier reset ----------------
// Thread layout in k_scan: tid = g*2 + half, g in [0,512), half in {0,1}.
// Wih5[(k4h*1024 + tid)*4 + kk] = Wih[g*256 + half*128 + k4h*4 + kk], k4h in [0,32)
// Whh5[(j  *1024 + tid)*4 + kk] = Whh[g*128 + half*64  + j*4   + kk], j   in [0,16)
__global__ __launch_bounds__(256) void k_prep(
    const float* __restrict__ Wih_f, const float* __restrict__ Wih_r,
    const float* __restrict__ Whh_f, const float* __restrict__ Whh_r,
    const float* __restrict__ bih_f, const float* __restrict__ bhh_f,
    const float* __restrict__ bih_r, const float* __restrict__ bhh_r,
    float* __restrict__ Wih5f, float* __restrict__ Wih5r,
    float* __restrict__ Whh5f, float* __restrict__ Whh5r,
    float* __restrict__ bsumf, float* __restrict__ bsumr, int* __restrict__ bar) {
  int id = blockIdx.x * 256 + threadIdx.x;  // 512*256 = 131072
  {
    int k4h = id >> 12;           // [0,32)
    int r = id & 4095;
    int t2 = r >> 2, kk = r & 3;
    int g = t2 >> 1, half = t2 & 1;
    int src = g * TD_N + half * 128 + k4h * 4 + kk;
    Wih5f[id] = Wih_f[src];
    Wih5r[id] = Wih_r[src];
  }
  if (id < 65536) {
    int j = id >> 12;             // [0,16)
    int r = id & 4095;
    int t2 = r >> 2, kk = r & 3;
    int g = t2 >> 1, half = t2 & 1;
    int src = g * H_N + half * 64 + j * 4 + kk;
    Whh5f[id] = Whh_f[src];
    Whh5r[id] = Whh_r[src];
  }
  if (id < 512) { bsumf[id] = bih_f[id] + bhh_f[id]; bsumr[id] = bih_r[id] + bhh_r[id]; }
  if (id == 0) bar[0] = 0;
}

// ---------------- k_lvl: topological levels; single wave, fully LDS-resident ----------------
__global__ __launch_bounds__(64) void k_lvl(const int* __restrict__ isin,
    const int* __restrict__ memb, int* __restrict__ fin,
    int* __restrict__ lstart, int* __restrict__ llist) {
  __shared__ int membS[A_N * M_N];        // 64 KB
  __shared__ int last[A_N];               // 4 KB
  __shared__ int cnt[A_N + 2];            // 4 KB
  __shared__ int cur[A_N + 2];            // 4 KB
  __shared__ short lvlS[A_N];             // 2 KB
  __shared__ unsigned char isinS[A_N];    // 1 KB
  __shared__ unsigned char cntm[A_N];     // 1 KB
  int lane = threadIdx.x;
  for (int i = lane; i < A_N * M_N; i += 64) membS[i] = memb[i] & (A_N - 1);
  for (int i = lane; i < A_N; i += 64) {
    isinS[i] = (unsigned char)(isin[i] != 0);
    last[i] = 0; cntm[i] = 0; lvlS[i] = 0;
  }
  for (int l = lane; l < A_N + 2; l += 64) cnt[l] = 0;
  __syncthreads();
  int lmax = 0;
  for (int s = 0; s < A_N; s++) {
    if (isinS[s]) {             // uniform branch (LDS broadcast)
      int li = 0, m = 0;
      if (lane < 16) { m = membS[s * M_N + lane]; li = last[m]; }
#pragma unroll
      for (int off = 8; off; off >>= 1) li = max(li, __shfl_xor(li, off));
      int L = __shfl(li, 0) + 1;
      if (lane < 16) { last[m] = L; cntm[m]++; }
      if (lane == 0) { lvlS[s] = (short)L; cnt[L]++; }
      lmax = max(lmax, L);
    }
  }
  if (lane == 0) {
    int acc = 0;
    for (int L = 1; L <= A_N + 1; L++) {
      cur[L] = acc; lstart[L] = acc;
      if (L <= A_N) acc += cnt[L];
    }
    lstart[0] = lmax;
    for (int s = 0; s < A_N; s++) {
      int L = lvlS[s];
      if (L > 0) llist[cur[L]++] = s;
    }
  }
  for (int i = lane; i < A_N; i += 64) fin[i] = cntm[i] & 1;
}

// ---------------- k_scan: single-dispatch level-parallel scan, Whh in VGPRs ----------------
// 16 WGs x 1024 threads, 2 WGs per step (one per dir). tid = g*2+half owns
// gate-column g, h-half `half`; Whh chunk = 16 float4 = 64 VGPRs.
// Occupancy forced to 1 WG/CU by LDS footprint (~86.6 KB > 160/2 KB), so the
// register budget is 128 VGPRs (4 waves/SIMD) -- the allocator cannot chase
// 2 WGs/CU (R8: it capped at 64 VGPRs and rematerialized the Whh hoist back
// into the loop = L2-streaming). asm-pin makes the hoist non-rematerializable.
#define SPAD 17408  // LDS pad (floats) to force 1 WG/CU
__global__ __launch_bounds__(1024)
void k_scan(
    float* __restrict__ thA, float* __restrict__ thB,
    const int* __restrict__ lstart, const int* __restrict__ llist,
    const int* __restrict__ memb, const int* __restrict__ req, int* __restrict__ bar,
    const float* __restrict__ Wih5f, const float* __restrict__ Wih5r,
    const float* __restrict__ Whh5f, const float* __restrict__ Whh5r,
    const float* __restrict__ bsumf, const float* __restrict__ bsumr) {
  __shared__ float S[16 * TD_N + SPAD];  // 16 KB used + 68 KB occupancy pad
  __shared__ float garr[4 * H_N];        // gates i,f,g,o 2 KB
  __shared__ float hb[H_N];              // current h 0.5 KB
  __shared__ int memb_s[16];
  __shared__ int par_s[16];
  int tid = threadIdx.x;
  int wg = blockIdx.x;
  int dir = wg & 1;
  int dmask = dir ? 15 : 0;
  int g = tid >> 1, half = tid & 1;
  const float4* Wih5 = (const float4*)(dir ? Wih5r : Wih5f);
  const float4* Whh5 = (const float4*)(dir ? Whh5r : Whh5f);
  float blo = (dir ? bsumr : bsumf)[g];
  int istanh = ((g >> 7) == 2);  // gate order i,f,g,o; g-chunk uses tanh
  // Whh chunk resident in registers for the whole kernel (64 VGPRs), asm-pinned
  float4 wcol[16];
#pragma unroll
  for (int j = 0; j < 16; j++) wcol[j] = Whh5[j * 1024 + tid];
#pragma unroll
  for (int j = 0; j < 16; j++)
    asm volatile("" : "+v"(wcol[j].x), "+v"(wcol[j].y), "+v"(wcol[j].z), "+v"(wcol[j].w));

  int lmax = lstart[0];
  int round = 0;
  for (int L = 1; L <= lmax; L++) {
    int i0 = lstart[L], i1 = lstart[L + 1];
    for (int pi = wg >> 1; pi < i1 - i0; pi += NWGC >> 1) {
      int s = llist[i0 + pi];
      if (tid < 16) { memb_s[tid] = memb[s * M_N + tid] & (A_N - 1); par_s[tid] = req[s * M_N + tid] & 1; }
      __syncthreads();
      {  // gather 16 member rows; stride-64 scalar layout: banks hit <=2x (free)
        int r = tid >> 6, t = tid & 63;
        const float* src = (par_s[r] ? thB : thA) + (size_t)memb_s[r] * TD_N;
        float* dst = S + r * TD_N;
#pragma unroll
        for (int q = 0; q < 4; q++) {
          int idx = q * 64 + t;
          dst[idx] = __hip_atomic_load(src + idx, __ATOMIC_RELAXED, __HIP_MEMORY_SCOPE_AGENT);
        }
      }
      __syncthreads();
      // ---- input transform: xa[t] = partial over this thread's k-half
      float xa[16];
#pragma unroll
      for (int t = 0; t < 16; t++) xa[t] = 0.0f;
      {
        const float4* S4 = (const float4*)S;
#pragma unroll 2
        for (int k4h = 0; k4h < 32; k4h++) {
          float4 wv = Wih5[k4h * 1024 + tid];
#pragma unroll
          for (int t = 0; t < 16; t++) {
            float4 sv = S4[(t ^ dmask) * 64 + half * 32 + k4h];
            xa[t] += dot4(sv, wv);
          }
        }
      }
      float xcol[16];
#pragma unroll
      for (int t = 0; t < 16; t++) xcol[t] = blo + xa[t] + __shfl_xor(xa[t], 1);
      if (tid < H_N) hb[tid] = 0.0f;
      float cst = 0.0f;
      __syncthreads();
      // ---- recurrence, fully unrolled (register arrays need static indices)
#pragma unroll
      for (int u = 0; u < 16; u++) {
        const float4* hb4 = (const float4*)hb;
        float zp0 = 0, zp1 = 0, zp2 = 0, zp3 = 0;
#pragma unroll
        for (int j = 0; j < 16; j += 4) {
          float4 h0 = hb4[half * 16 + j + 0];
          float4 h1 = hb4[half * 16 + j + 1];
          float4 h2 = hb4[half * 16 + j + 2];
          float4 h3 = hb4[half * 16 + j + 3];
          zp0 += dot4(h0, wcol[j + 0]);
          zp1 += dot4(h1, wcol[j + 1]);
          zp2 += dot4(h2, wcol[j + 2]);
          zp3 += dot4(h3, wcol[j + 3]);
        }
        float zp = (zp0 + zp1) + (zp2 + zp3);
        float z = xcol[u] + zp + __shfl_xor(zp, 1);
        float gate = istanh ? tanhf(z) : sigf(z);
        if (!(tid & 1)) garr[g] = gate;
        __syncthreads();
        if (tid < 256 && !(tid & 1)) {
          int g0 = tid >> 1;  // hidden index [0,128)
          cst = garr[H_N + g0] * cst + garr[g0] * garr[2 * H_N + g0];
          float hv = garr[3 * H_N + g0] * tanhf(cst);
          hb[g0] = hv;
          int r2 = u ^ dmask;                 // fwd: u; bwd: 15-u (rev-aligned)
          float* dst = par_s[r2] ? thA : thB; // write opposite parity buffer
          __hip_atomic_store(dst + (size_t)memb_s[r2] * TD_N + dir * H_N + g0, hv,
                             __ATOMIC_RELAXED, __HIP_MEMORY_SCOPE_AGENT);
        }
        __syncthreads();
      }
    }
    // ---- grid barrier: syncthreads (drains vmcnt for all threads) + relaxed add/poll
    round++;
    __syncthreads();
    if (tid == 0) {
      __hip_atomic_fetch_add(bar, 1, __ATOMIC_RELAXED, __HIP_MEMORY_SCOPE_AGENT);
      int target = round * NWGC;
      int tries = 0;
      while (__hip_atomic_load(bar, __ATOMIC_RELAXED, __HIP_MEMORY_SCOPE_AGENT) < target) {
        __builtin_amdgcn_s_sleep(1);
        if (++tries > (1 << 17)) break;  // failsafe: wrong-answer beats hang
      }
    }
    __syncthreads();
  }
}

// ---------------- k_actor2: acts = tanh(LN(LN(relu(th)@W3+b3)@W4+b4)) ----------------
__global__ __launch_bounds__(256) void k_actor2(const float* __restrict__ thA, const float* __restrict__ thB,
    const int* __restrict__ fin,
    const float* __restrict__ W3, const float* __restrict__ b3,
    const float* __restrict__ g3, const float* __restrict__ bt3,
    const float* __restrict__ W4, const float* __restrict__ b4,
    const float* __restrict__ g4, const float* __restrict__ bt4,
    float* __restrict__ out) {
  __shared__ float Hs[4 * TD_N];
  __shared__ float H3[4 * TD_N];
  __shared__ float red[4][4][2];
  int tid = threadIdx.x;
  int r0 = blockIdx.x * 4;
  int j = tid;
  for (int i = tid; i < 4 * TD_N; i += 256) {
    int r = i >> 8, col = i & 255;
    int row = r0 + r;
    const float* src = (fin[row] ? thB : thA) + (size_t)row * TD_N + col;
    float v = __hip_atomic_load(src, __ATOMIC_RELAXED, __HIP_MEMORY_SCOPE_AGENT);
    Hs[i] = fmaxf(v, 0.0f);
  }
  __syncthreads();  // all reads of own rows complete before any write below
  float z[4] = {0, 0, 0, 0};
  {
    const float4* S4 = (const float4*)Hs;
    for (int k4 = 0; k4 < 64; k4++) {
      float w0 = W3[(k4 * 4 + 0) * TD_N + j];
      float w1 = W3[(k4 * 4 + 1) * TD_N + j];
      float w2 = W3[(k4 * 4 + 2) * TD_N + j];
      float w3v = W3[(k4 * 4 + 3) * TD_N + j];
#pragma unroll
      for (int r = 0; r < 4; r++) {
        float4 sv = S4[r * 64 + k4];
        z[r] += sv.x * w0 + sv.y * w1 + sv.z * w2 + sv.w * w3v;
      }
    }
  }
  for (int r = 0; r < 4; r++) z[r] += b3[j];
  int w = tid >> 6, lane = tid & 63;
  for (int r = 0; r < 4; r++) {
    float v = z[r], v2 = z[r] * z[r];
    for (int off = 32; off; off >>= 1) { v += __shfl_down(v, off); v2 += __shfl_down(v2, off); }
    if (lane == 0) { red[r][w][0] = v; red[r][w][1] = v2; }
  }
  __syncthreads();
  for (int r = 0; r < 4; r++) {
    float sm = red[r][0][0] + red[r][1][0] + red[r][2][0] + red[r][3][0];
    float sq = red[r][0][1] + red[r][1][1] + red[r][2][1] + red[r][3][1];
    float mean = sm * (1.0f / TD_N);
    float var = sq * (1.0f / TD_N) - mean * mean;
    float rs = 1.0f / sqrtf(var + 1e-5f);
    H3[r * TD_N + j] = (z[r] - mean) * rs * g3[j] + bt3[j];
  }
  __syncthreads();
  float z2a[4] = {0, 0, 0, 0};
  {
    const float4* S4 = (const float4*)H3;
    for (int k4 = 0; k4 < 64; k4++) {
      float w0 = W4[(k4 * 4 + 0) * TD_N + j];
      float w1 = W4[(k4 * 4 + 1) * TD_N + j];
      float w2 = W4[(k4 * 4 + 2) * TD_N + j];
      float w3v = W4[(k4 * 4 + 3) * TD_N + j];
#pragma unroll
      for (int r = 0; r < 4; r++) {
        float4 sv = S4[r * 64 + k4];
        z2a[r] += sv.x * w0 + sv.y * w1 + sv.z * w2 + sv.w * w3v;
      }
    }
  }
  for (int r = 0; r < 4; r++) z2a[r] += b4[j];
  __syncthreads();
  for (int r = 0; r < 4; r++) {
    float v = z2a[r], v2 = z2a[r] * z2a[r];
    for (int off = 32; off; off >>= 1) { v += __shfl_down(v, off); v2 += __shfl_down(v2, off); }
    if (lane == 0) { red[r][w][0] = v; red[r][w][1] = v2; }
  }
  __syncthreads();
  for (int r = 0; r < 4; r++) {
    float sm = red[r][0][0] + red[r][1][0] + red[r][2][0] + red[r][3][0];
    float sq = red[r][0][1] + red[r][1][1] + red[r][2][1] + red[r][3][1];
    float mean = sm * (1.0f / TD_N);
    float var = sq * (1.0f / TD_N) - mean * mean;
    float rs = 1.0f / sqrtf(var + 1e-5f);
    float val = (z2a[r] - mean) * rs * g4[j] + bt4[j];
    out[(size_t)(r0 + r) * TD_N + j] = tanhf(val);
  }
}

extern "C" void kernel_launch(void* const* d_in, const int* in_sizes, int n_in,
                              void* d_out, int out_size, void* d_ws, size_t ws_size,
                              hipStream_t stream) {
  const float* obs = (const float*)d_in[0];
  const unsigned char* C = (const unsigned char*)d_in[1];
  const float* W1 = (const float*)d_in[2];  const float* b1 = (const float*)d_in[3];
  const float* g1 = (const float*)d_in[4];  const float* bt1 = (const float*)d_in[5];
  const float* W2 = (const float*)d_in[6];  const float* b2 = (const float*)d_in[7];
  const float* g2 = (const float*)d_in[8];  const float* bt2 = (const float*)d_in[9];
  const float* aW1 = (const float*)d_in[10]; const float* ab1 = (const float*)d_in[11];
  const float* aW2 = (const float*)d_in[12]; const float* ab2 = (const float*)d_in[13];
  const float* aW3 = (const float*)d_in[14]; const float* ab3 = (const float*)d_in[15];
  const float* Wih_f = (const float*)d_in[16]; const float* Whh_f = (const float*)d_in[17];
  const float* bih_f = (const float*)d_in[18]; const float* bhh_f = (const float*)d_in[19];
  const float* Wih_r = (const float*)d_in[20]; const float* Whh_r = (const float*)d_in[21];
  const float* bih_r = (const float*)d_in[22]; const float* bhh_r = (const float*)d_in[23];
  const float* W3 = (const float*)d_in[24]; const float* b3 = (const float*)d_in[25];
  const float* g3 = (const float*)d_in[26]; const float* bt3 = (const float*)d_in[27];
  const float* W4 = (const float*)d_in[28]; const float* b4 = (const float*)d_in[29];
  const float* g4 = (const float*)d_in[30]; const float* bt4 = (const float*)d_in[31];
  float* out = (float*)d_out;

  // Workspace layout (float offsets). t_buf overlaps thB (dead before k_scan).
  float* ws = (float*)d_ws;
  float* Wih5f = ws;                  // 131072
  float* Wih5r = ws + 131072;         // 131072
  float* Whh5f = ws + 262144;         // 65536
  float* Whh5r = ws + 327680;         // 65536
  float* bsumf = ws + 393216;         // 512
  float* bsumr = ws + 393728;         // 512
  float* thB   = ws + 394240;         // 262144 (parity-1 thoughts buffer)
  float* t_buf = ws + 394240;         // overlap: used only before k_prep/k_scan
  int* ibase   = (int*)(ws + 656384);
  int* membi   = ibase;               // 16384
  int* reqi    = ibase + 16384;       // 16384
  int* isin    = ibase + 32768;       // 1024
  int* flag    = ibase + 33792;       // 64
  int* fin     = ibase + 33856;       // 1024
  int* lstart  = ibase + 34880;       // 1027 (pad to 1088)
  int* llist   = ibase + 35968;       // 1024
  int* bar     = ibase + 36992;       // 64
  size_t need = (size_t)(656384 + 37056 + 64) * 4;  // ~2.77 MB
  if (ws_size < need) return;  // diagnosable absmax-fail instead of a fault

  (void)in_sizes; (void)n_in; (void)out_size;

  float* thA = out;  // parity-0 thoughts buffer aliases d_out

  k_cdet<<<1, 64, 0, stream>>>(C, flag);
  k_actor1a<<<256, 256, 0, stream>>>(obs, W1, b1, g1, bt1, t_buf);
  k_actor1b<<<256, 256, 0, stream>>>(t_buf, W2, b2, g2, bt2, thA);
  k_att<<<256, 256, 0, stream>>>(thA, aW1, ab1, aW2, ab2, aW3, ab3, isin);
  k_memb<<<1024, 64, 0, stream>>>(C, flag, membi);
  k_req<<<1024, 256, 0, stream>>>(C, flag, membi, isin, reqi);
  k_prep<<<512, 256, 0, stream>>>(Wih_f, Wih_r, Whh_f, Whh_r, bih_f, bhh_f, bih_r, bhh_r,
                                  Wih5f, Wih5r, Whh5f, Whh5r, bsumf, bsumr, bar);
  k_lvl<<<1, 64, 0, stream>>>(isin, membi, fin, lstart, llist);
  k_scan<<<NWGC, 1024, 0, stream>>>(thA, thB, lstart, llist, membi, reqi, bar,
                                    Wih5f, Wih5r, Whh5f, Whh5r, bsumf, bsumr);
  k_actor2<<<256, 256, 0, stream>>>(thA, thB, fin, W3, b3, g3, bt3, W4, b4, g4, bt4, out);
}

// Round 10
// 15775.352 us; speedup vs baseline: 1.4130x; 1.4130x over previous
//
#include <hip/hip_runtime.h>
#include <cstdint>
#include <cstddef>
#include <math.h>

#define A_N   1024
#define OBS_N 2048
#define TD_N  256
#define H_N   128
#define M_N   16
#define AE_N  64
#define NWGC  16   // k_scan grid: 16 WGs (8 parallel steps), 1 WG/CU (LDS-forced)

__device__ __forceinline__ float sigf(float x) { return 1.0f / (1.0f + expf(-x)); }
__device__ __forceinline__ float dot4(float4 a, float4 b) {
  return a.x * b.x + a.y * b.y + a.z * b.z + a.w * b.w;
}

// C may arrive as uint8 (1B/elem) or int32 (4B/elem). Detect on device.
__device__ __forceinline__ bool c_at(const unsigned char* C, int as_int, size_t idx) {
  return as_int ? (((const int*)C)[idx] != 0) : (C[idx] != 0);
}

__global__ __launch_bounds__(64) void k_cdet(const unsigned char* __restrict__ C, int* __restrict__ flag) {
  int lane = threadIdx.x;
  int cnt = 0;
  for (int i = lane; i < 4096; i += 64) cnt += (C[i] != 0) ? 1 : 0;
  for (int off = 32; off; off >>= 1) cnt += __shfl_down(cnt, off);
  if (lane == 0) flag[0] = (cnt < 40) ? 1 : 0;
}

// ---------------- k1: t = relu(LN(obs@W1 + b1)) ----------------
__global__ __launch_bounds__(256) void k_actor1a(const float* __restrict__ obs,
    const float* __restrict__ W1, const float* __restrict__ b1,
    const float* __restrict__ g1, const float* __restrict__ bt1,
    float* __restrict__ tout) {
  __shared__ float S[4 * OBS_N];
  __shared__ float red[4][4][2];
  int tid = threadIdx.x;
  int r0 = blockIdx.x * 4;
  {
    const float4* src = (const float4*)(obs + (size_t)r0 * OBS_N);
    float4* dst = (float4*)S;
    for (int i = tid; i < 4 * OBS_N / 4; i += 256) dst[i] = src[i];
  }
  __syncthreads();
  int j = tid;
  float acc0 = 0, acc1 = 0, acc2 = 0, acc3 = 0;
  const float4* S4 = (const float4*)S;
  for (int k4 = 0; k4 < OBS_N / 4; k4++) {
    float w0 = W1[(k4 * 4 + 0) * TD_N + j];
    float w1 = W1[(k4 * 4 + 1) * TD_N + j];
    float w2 = W1[(k4 * 4 + 2) * TD_N + j];
    float w3 = W1[(k4 * 4 + 3) * TD_N + j];
    float4 s0 = S4[0 * 512 + k4], s1 = S4[1 * 512 + k4], s2 = S4[2 * 512 + k4], s3 = S4[3 * 512 + k4];
    acc0 += s0.x * w0 + s0.y * w1 + s0.z * w2 + s0.w * w3;
    acc1 += s1.x * w0 + s1.y * w1 + s1.z * w2 + s1.w * w3;
    acc2 += s2.x * w0 + s2.y * w1 + s2.z * w2 + s2.w * w3;
    acc3 += s3.x * w0 + s3.y * w1 + s3.z * w2 + s3.w * w3;
  }
  float z[4] = {acc0 + b1[j], acc1 + b1[j], acc2 + b1[j], acc3 + b1[j]};
  int w = tid >> 6, lane = tid & 63;
  for (int r = 0; r < 4; r++) {
    float v = z[r], v2 = z[r] * z[r];
    for (int off = 32; off; off >>= 1) { v += __shfl_down(v, off); v2 += __shfl_down(v2, off); }
    if (lane == 0) { red[r][w][0] = v; red[r][w][1] = v2; }
  }
  __syncthreads();
  for (int r = 0; r < 4; r++) {
    float sm = red[r][0][0] + red[r][1][0] + red[r][2][0] + red[r][3][0];
    float sq = red[r][0][1] + red[r][1][1] + red[r][2][1] + red[r][3][1];
    float mean = sm * (1.0f / TD_N);
    float var = sq * (1.0f / TD_N) - mean * mean;
    float rs = 1.0f / sqrtf(var + 1e-5f);
    float val = (z[r] - mean) * rs * g1[j] + bt1[j];
    tout[(size_t)(r0 + r) * TD_N + j] = fmaxf(val, 0.0f);
  }
}

// ---------------- k2: thoughts = LN(t@W2 + b2) -> thA (= d_out) ----------------
__global__ __launch_bounds__(256) void k_actor1b(const float* __restrict__ tin,
    const float* __restrict__ W2, const float* __restrict__ b2,
    const float* __restrict__ g2, const float* __restrict__ bt2,
    float* __restrict__ th) {
  __shared__ float S[4 * TD_N];
  __shared__ float red[4][4][2];
  int tid = threadIdx.x;
  int r0 = blockIdx.x * 4;
  for (int i = tid; i < 4 * TD_N; i += 256) S[i] = tin[(size_t)r0 * TD_N + i];
  __syncthreads();
  int j = tid;
  float z[4] = {0, 0, 0, 0};
  const float4* S4 = (const float4*)S;
  for (int k4 = 0; k4 < TD_N / 4; k4++) {
    float w0 = W2[(k4 * 4 + 0) * TD_N + j];
    float w1 = W2[(k4 * 4 + 1) * TD_N + j];
    float w2v = W2[(k4 * 4 + 2) * TD_N + j];
    float w3 = W2[(k4 * 4 + 3) * TD_N + j];
#pragma unroll
    for (int r = 0; r < 4; r++) {
      float4 sv = S4[r * 64 + k4];
      z[r] += sv.x * w0 + sv.y * w1 + sv.z * w2v + sv.w * w3;
    }
  }
  for (int r = 0; r < 4; r++) z[r] += b2[j];
  int w = tid >> 6, lane = tid & 63;
  for (int r = 0; r < 4; r++) {
    float v = z[r], v2 = z[r] * z[r];
    for (int off = 32; off; off >>= 1) { v += __shfl_down(v, off); v2 += __shfl_down(v2, off); }
    if (lane == 0) { red[r][w][0] = v; red[r][w][1] = v2; }
  }
  __syncthreads();
  for (int r = 0; r < 4; r++) {
    float sm = red[r][0][0] + red[r][1][0] + red[r][2][0] + red[r][3][0];
    float sq = red[r][0][1] + red[r][1][1] + red[r][2][1] + red[r][3][1];
    float mean = sm * (1.0f / TD_N);
    float var = sq * (1.0f / TD_N) - mean * mean;
    float rs = 1.0f / sqrtf(var + 1e-5f);
    th[(size_t)(r0 + r) * TD_N + j] = (z[r] - mean) * rs * g2[j] + bt2[j];
  }
}

// ---------------- k3: attention unit -> is_init (fp64: x>0 decision is razor-thin) ----------------
__global__ __launch_bounds__(256) void k_att(const float* __restrict__ th,
    const float* __restrict__ aW1, const float* __restrict__ ab1,
    const float* __restrict__ aW2, const float* __restrict__ ab2,
    const float* __restrict__ aW3, const float* __restrict__ ab3,
    int* __restrict__ isin) {
  __shared__ float S[4 * TD_N];
  __shared__ double A1[4 * AE_N];
  __shared__ double A2[4 * AE_N];
  int tid = threadIdx.x;
  int r0 = blockIdx.x * 4;
  for (int i = tid; i < 4 * TD_N; i += 256) S[i] = th[(size_t)r0 * TD_N + i];
  __syncthreads();
  int r = tid >> 6, c = tid & 63;
  double acc = 0;
  for (int k = 0; k < TD_N; k++) acc += (double)S[r * TD_N + k] * (double)aW1[k * AE_N + c];
  acc += (double)ab1[c];
  A1[r * AE_N + c] = acc > 0.0 ? acc : 0.0;
  __syncthreads();
  acc = 0;
  for (int k = 0; k < AE_N; k++) acc += A1[r * AE_N + k] * (double)aW2[k * AE_N + c];
  acc += (double)ab2[c];
  A2[r * AE_N + c] = acc > 0.0 ? acc : 0.0;
  __syncthreads();
  double p = A2[r * AE_N + c] * (double)aW3[c];
  for (int off = 32; off; off >>= 1) p += __shfl_down(p, off);
  if (c == 0) isin[r0 + r] = ((p + (double)ab3[0]) > 0.0) ? 1 : 0;
}

// ---------------- k_memb: member indices (ascending) per row ----------------
__global__ __launch_bounds__(64) void k_memb(const unsigned char* __restrict__ C,
    const int* __restrict__ flag, int* __restrict__ memb) {
  int s = blockIdx.x, lane = threadIdx.x;
  int as_int = flag[0];
  if (lane < M_N) memb[s * M_N + lane] = lane;  // safe defaults (never poison)
  __syncthreads();
  int base = 0;
  for (int ch = 0; ch < 16; ch++) {
    int col = ch * 64 + lane;
    bool v = c_at(C, as_int, (size_t)s * A_N + col);
    unsigned long long m = __ballot(v);
    if (v) {
      int pos = base + __popcll(m & ((1ull << lane) - 1ull));
      if (pos < M_N) memb[s * M_N + pos] = col;
    }
    base += __popcll(m);
  }
}

// ---------------- k_req: write ordinal per (step, member slot) ----------------
__global__ __launch_bounds__(256) void k_req(const unsigned char* __restrict__ C,
    const int* __restrict__ flag, const int* __restrict__ memb,
    const int* __restrict__ isin, int* __restrict__ req) {
  __shared__ int Ls[A_N];
  int s = blockIdx.x, tid = threadIdx.x;
  int as_int = flag[0];
  for (int i = tid; i < A_N; i += 256) Ls[i] = isin[i];
  __syncthreads();
  int i = tid >> 4, sub = tid & 15;
  int m = memb[s * M_N + i] & (A_N - 1);
  int cnt = 0;
  for (int s2 = sub; s2 < s; s2 += 16)
    if (Ls[s2] && c_at(C, as_int, (size_t)s2 * A_N + m)) cnt++;
  for (int off = 1; off < 16; off <<= 1) cnt += __shfl_xor(cnt, off);
  if (sub == 0) req[s * M_N + i] = cnt;
}

// ---------------- k_prep: k-major weight re-layouts (R5/R6 layout), bias sums, bar reset ----------------
// Wih4[(k4*512+g)*4+kk] = Wih[g*256 + k4*4 + kk], k4 in [0,64)
// Whh4[(k4*512+g)*4+kk] = Whh[g*128 + k4*4 + kk], k4 in [0,32)
__global__ __launch_bounds__(256) void k_prep(
    const float* __restrict__ Wih_f, const float* __restrict__ Wih_r,
    const float* __restrict__ Whh_f, const float* __restrict__ Whh_r,
    const float* __restrict__ bih_f, const float* __restrict__ bhh_f,
    const float* __restrict__ bih_r, const float* __restrict__ bhh_r,
    float* __restrict__ Wih4f, float* __restrict__ Wih4r,
    float* __restrict__ Whh4f, float* __restrict__ Whh4r,
    float* __restrict__ bsumf, float* __restrict__ bsumr, int* __restrict__ bar) {
  int id = blockIdx.x * 256 + threadIdx.x;  // 512*256 = 131072
  {
    int kk = id & 3, g = (id >> 2) & 511, k4 = id >> 11;
    Wih4f[id] = Wih_f[g * TD_N + k4 * 4 + kk];
    Wih4r[id] = Wih_r[g * TD_N + k4 * 4 + kk];
  }
  if (id < 65536) {
    int kk = id & 3, g = (id >> 2) & 511, k4 = id >> 11;
    Whh4f[id] = Whh_f[g * H_N + k4 * 4 + kk];
    Whh4r[id] = Whh_r[g * H_N + k4 * 4 + kk];
  }
  if (id < 512) { bsumf[id] = bih_f[id] + bhh_f[id]; bsumr[id] = bih_r[id] + bhh_r[id]; }
  if (id == 0) bar[0] = 0;
}

// ---------------- k_lvl: topological levels; single wave, fully LDS-resident ----------------
__global__ __launch_bounds__(64) void k_lvl(const int* __restrict__ isin,
    const int* __restrict__ memb, int* __restrict__ fin,
    int* __restrict__ lstart, int* __restrict__ llist) {
  __shared__ int membS[A_N * M_N];        // 64 KB
  __shared__ int last[A_N];               // 4 KB
  __shared__ int cnt[A_N + 2];            // 4 KB
  __shared__ int cur[A_N + 2];            // 4 KB
  __shared__ short lvlS[A_N];             // 2 KB
  __shared__ unsigned char isinS[A_N];    // 1 KB
  __shared__ unsigned char cntm[A_N];     // 1 KB
  int lane = threadIdx.x;
  for (int i = lane; i < A_N * M_N; i += 64) membS[i] = memb[i] & (A_N - 1);
  for (int i = lane; i < A_N; i += 64) {
    isinS[i] = (unsigned char)(isin[i] != 0);
    last[i] = 0; cntm[i] = 0; lvlS[i] = 0;
  }
  for (int l = lane; l < A_N + 2; l += 64) cnt[l] = 0;
  __syncthreads();
  int lmax = 0;
  for (int s = 0; s < A_N; s++) {
    if (isinS[s]) {             // uniform branch (LDS broadcast)
      int li = 0, m = 0;
      if (lane < 16) { m = membS[s * M_N + lane]; li = last[m]; }
#pragma unroll
      for (int off = 8; off; off >>= 1) li = max(li, __shfl_xor(li, off));
      int L = __shfl(li, 0) + 1;
      if (lane < 16) { last[m] = L; cntm[m]++; }
      if (lane == 0) { lvlS[s] = (short)L; cnt[L]++; }
      lmax = max(lmax, L);
    }
  }
  if (lane == 0) {
    int acc = 0;
    for (int L = 1; L <= A_N + 1; L++) {
      cur[L] = acc; lstart[L] = acc;
      if (L <= A_N) acc += cnt[L];
    }
    lstart[0] = lmax;
    for (int s = 0; s < A_N; s++) {
      int L = lvlS[s];
      if (L > 0) llist[cur[L]++] = s;
    }
  }
  for (int i = lane; i < A_N; i += 64) fin[i] = cntm[i] & 1;
}

// ---------------- k_scan: single-dispatch level-parallel scan, Whh in VGPRs ----------------
// 16 WGs x 512 threads, 2 WGs per step (one per dir). Thread tid owns gate
// column tid of its dir; its full Whh column = 32 float4 = 128 VGPRs, loaded
// once and asm-pinned. Occupancy: LDS ~85 KB forces 1 WG/CU -> 8 waves/CU ->
// 2 waves/SIMD -> 256-VGPR budget (512-thread WGs got 128+ in R5/R6; the
// 1024-thread configs were hard-capped at 64 in R7-R9 and always spilled).
// u-loop fully unrolled: xcol/wcol/hb-buf indices all compile-time (rule #20).
#define SPAD 16384  // LDS pad (floats) -> S block 80 KB; total ~85 KB > 160/2
__global__ __launch_bounds__(512)
void k_scan(
    float* __restrict__ thA, float* __restrict__ thB,
    const int* __restrict__ lstart, const int* __restrict__ llist,
    const int* __restrict__ memb, const int* __restrict__ req, int* __restrict__ bar,
    const float* __restrict__ Wih4f, const float* __restrict__ Wih4r,
    const float* __restrict__ Whh4f, const float* __restrict__ Whh4r,
    const float* __restrict__ bsumf, const float* __restrict__ bsumr) {
  __shared__ float S[16 * TD_N + SPAD];  // 16 KB used + 64 KB occupancy pad
  __shared__ float garr[4 * H_N];        // gates i,f,g,o 2 KB
  __shared__ float hb[2 * H_N];          // h ping-pong 1 KB
  __shared__ int memb_s[16];
  __shared__ int par_s[16];
  int tid = threadIdx.x;
  int wg = blockIdx.x;
  int dir = wg & 1;
  int dmask = dir ? 15 : 0;
  const float4* Wih4 = (const float4*)(dir ? Wih4r : Wih4f);
  const float4* Whh4 = (const float4*)(dir ? Whh4r : Whh4f);
  float blo = (dir ? bsumr : bsumf)[tid];
  int istanh = ((tid >> 7) == 2);  // gate order i,f,g,o; g-chunk uses tanh
  // Full Whh column resident in registers (128 VGPRs), asm-pinned against remat
  float4 wcol[32];
#pragma unroll
  for (int j = 0; j < 32; j++) wcol[j] = Whh4[j * 512 + tid];
#pragma unroll
  for (int j = 0; j < 32; j++)
    asm volatile("" : "+v"(wcol[j].x), "+v"(wcol[j].y), "+v"(wcol[j].z), "+v"(wcol[j].w));

  int lmax = lstart[0];
  int round = 0;
  for (int L = 1; L <= lmax; L++) {
    int i0 = lstart[L], i1 = lstart[L + 1];
    for (int pi = wg >> 1; pi < i1 - i0; pi += NWGC >> 1) {
      int s = llist[i0 + pi];
      if (tid < 16) { memb_s[tid] = memb[s * M_N + tid] & (A_N - 1); par_s[tid] = req[s * M_N + tid] & 1; }
      __syncthreads();
      {  // gather 16 member rows (coherent L3 loads); conflict-free q*32+p layout
        int r = tid >> 5, p = tid & 31;
        const float* src = (par_s[r] ? thB : thA) + (size_t)memb_s[r] * TD_N;
        float* dst = S + r * TD_N;
#pragma unroll
        for (int q = 0; q < 8; q++)
          dst[q * 32 + p] = __hip_atomic_load(src + q * 32 + p, __ATOMIC_RELAXED, __HIP_MEMORY_SCOPE_AGENT);
      }
      __syncthreads();
      // ---- input transform: xa[t] = bsum + seq[t] . Wih[:,tid]
      float xa[16];
#pragma unroll
      for (int t = 0; t < 16; t++) xa[t] = blo;
      {
        const float4* S4 = (const float4*)S;
#pragma unroll 2
        for (int k4 = 0; k4 < 64; k4++) {
          float4 wv = Wih4[k4 * 512 + tid];
#pragma unroll
          for (int t = 0; t < 16; t++) {
            float4 sv = S4[(t ^ dmask) * 64 + k4];
            xa[t] += dot4(sv, wv);
          }
        }
      }
      if (tid < H_N) hb[tid] = 0.0f;  // h0 = 0 in buf 0
      float cst = 0.0f;
      __syncthreads();
      // ---- recurrence, fully unrolled; Whh from pinned registers
#pragma unroll
      for (int u = 0; u < 16; u++) {
        const float4* hp4 = (const float4*)(hb + (u & 1) * H_N);
        float zp0 = 0, zp1 = 0, zp2 = 0, zp3 = 0;
#pragma unroll
        for (int j = 0; j < 32; j += 4) {
          zp0 += dot4(hp4[j + 0], wcol[j + 0]);
          zp1 += dot4(hp4[j + 1], wcol[j + 1]);
          zp2 += dot4(hp4[j + 2], wcol[j + 2]);
          zp3 += dot4(hp4[j + 3], wcol[j + 3]);
        }
        float z = xa[u] + (zp0 + zp1) + (zp2 + zp3);
        garr[tid] = istanh ? tanhf(z) : sigf(z);
        __syncthreads();
        if (tid < H_N) {
          cst = garr[H_N + tid] * cst + garr[tid] * garr[2 * H_N + tid];
          float hv = garr[3 * H_N + tid] * tanhf(cst);
          hb[((u + 1) & 1) * H_N + tid] = hv;
          int r2 = u ^ dmask;                 // fwd: u; bwd: 15-u (rev-aligned)
          float* dst = par_s[r2] ? thA : thB; // write opposite parity buffer
          __hip_atomic_store(dst + (size_t)memb_s[r2] * TD_N + dir * H_N + tid, hv,
                             __ATOMIC_RELAXED, __HIP_MEMORY_SCOPE_AGENT);
        }
        __syncthreads();
      }
    }
    // ---- grid barrier: syncthreads (drains vmcnt for all threads) + relaxed add/poll
    round++;
    __syncthreads();
    if (tid == 0) {
      __hip_atomic_fetch_add(bar, 1, __ATOMIC_RELAXED, __HIP_MEMORY_SCOPE_AGENT);
      int target = round * NWGC;
      int tries = 0;
      while (__hip_atomic_load(bar, __ATOMIC_RELAXED, __HIP_MEMORY_SCOPE_AGENT) < target) {
        __builtin_amdgcn_s_sleep(1);
        if (++tries > (1 << 17)) break;  // failsafe: wrong-answer beats hang
      }
    }
    __syncthreads();
  }
}

// ---------------- k_actor2: acts = tanh(LN(LN(relu(th)@W3+b3)@W4+b4)) ----------------
__global__ __launch_bounds__(256) void k_actor2(const float* __restrict__ thA, const float* __restrict__ thB,
    const int* __restrict__ fin,
    const float* __restrict__ W3, const float* __restrict__ b3,
    const float* __restrict__ g3, const float* __restrict__ bt3,
    const float* __restrict__ W4, const float* __restrict__ b4,
    const float* __restrict__ g4, const float* __restrict__ bt4,
    float* __restrict__ out) {
  __shared__ float Hs[4 * TD_N];
  __shared__ float H3[4 * TD_N];
  __shared__ float red[4][4][2];
  int tid = threadIdx.x;
  int r0 = blockIdx.x * 4;
  int j = tid;
  for (int i = tid; i < 4 * TD_N; i += 256) {
    int r = i >> 8, col = i & 255;
    int row = r0 + r;
    const float* src = (fin[row] ? thB : thA) + (size_t)row * TD_N + col;
    float v = __hip_atomic_load(src, __ATOMIC_RELAXED, __HIP_MEMORY_SCOPE_AGENT);
    Hs[i] = fmaxf(v, 0.0f);
  }
  __syncthreads();  // all reads of own rows complete before any write below
  float z[4] = {0, 0, 0, 0};
  {
    const float4* S4 = (const float4*)Hs;
    for (int k4 = 0; k4 < 64; k4++) {
      float w0 = W3[(k4 * 4 + 0) * TD_N + j];
      float w1 = W3[(k4 * 4 + 1) * TD_N + j];
      float w2 = W3[(k4 * 4 + 2) * TD_N + j];
      float w3v = W3[(k4 * 4 + 3) * TD_N + j];
#pragma unroll
      for (int r = 0; r < 4; r++) {
        float4 sv = S4[r * 64 + k4];
        z[r] += sv.x * w0 + sv.y * w1 + sv.z * w2 + sv.w * w3v;
      }
    }
  }
  for (int r = 0; r < 4; r++) z[r] += b3[j];
  int w = tid >> 6, lane = tid & 63;
  for (int r = 0; r < 4; r++) {
    float v = z[r], v2 = z[r] * z[r];
    for (int off = 32; off; off >>= 1) { v += __shfl_down(v, off); v2 += __shfl_down(v2, off); }
    if (lane == 0) { red[r][w][0] = v; red[r][w][1] = v2; }
  }
  __syncthreads();
  for (int r = 0; r < 4; r++) {
    float sm = red[r][0][0] + red[r][1][0] + red[r][2][0] + red[r][3][0];
    float sq = red[r][0][1] + red[r][1][1] + red[r][2][1] + red[r][3][1];
    float mean = sm * (1.0f / TD_N);
    float var = sq * (1.0f / TD_N) - mean * mean;
    float rs = 1.0f / sqrtf(var + 1e-5f);
    H3[r * TD_N + j] = (z[r] - mean) * rs * g3[j] + bt3[j];
  }
  __syncthreads();
  float z2a[4] = {0, 0, 0, 0};
  {
    const float4* S4 = (const float4*)H3;
    for (int k4 = 0; k4 < 64; k4++) {
      float w0 = W4[(k4 * 4 + 0) * TD_N + j];
      float w1 = W4[(k4 * 4 + 1) * TD_N + j];
      float w2 = W4[(k4 * 4 + 2) * TD_N + j];
      float w3v = W4[(k4 * 4 + 3) * TD_N + j];
#pragma unroll
      for (int r = 0; r < 4; r++) {
        float4 sv = S4[r * 64 + k4];
        z2a[r] += sv.x * w0 + sv.y * w1 + sv.z * w2 + sv.w * w3v;
      }
    }
  }
  for (int r = 0; r < 4; r++) z2a[r] += b4[j];
  __syncthreads();
  for (int r = 0; r < 4; r++) {
    float v = z2a[r], v2 = z2a[r] * z2a[r];
    for (int off = 32; off; off >>= 1) { v += __shfl_down(v, off); v2 += __shfl_down(v2, off); }
    if (lane == 0) { red[r][w][0] = v; red[r][w][1] = v2; }
  }
  __syncthreads();
  for (int r = 0; r < 4; r++) {
    float sm = red[r][0][0] + red[r][1][0] + red[r][2][0] + red[r][3][0];
    float sq = red[r][0][1] + red[r][1][1] + red[r][2][1] + red[r][3][1];
    float mean = sm * (1.0f / TD_N);
    float var = sq * (1.0f / TD_N) - mean * mean;
    float rs = 1.0f / sqrtf(var + 1e-5f);
    float val = (z2a[r] - mean) * rs * g4[j] + bt4[j];
    out[(size_t)(r0 + r) * TD_N + j] = tanhf(val);
  }
}

extern "C" void kernel_launch(void* const* d_in, const int* in_sizes, int n_in,
                              void* d_out, int out_size, void* d_ws, size_t ws_size,
                              hipStream_t stream) {
  const float* obs = (const float*)d_in[0];
  const unsigned char* C = (const unsigned char*)d_in[1];
  const float* W1 = (const float*)d_in[2];  const float* b1 = (const float*)d_in[3];
  const float* g1 = (const float*)d_in[4];  const float* bt1 = (const float*)d_in[5];
  const float* W2 = (const float*)d_in[6];  const float* b2 = (const float*)d_in[7];
  const float* g2 = (const float*)d_in[8];  const float* bt2 = (const float*)d_in[9];
  const float* aW1 = (const float*)d_in[10]; const float* ab1 = (const float*)d_in[11];
  const float* aW2 = (const float*)d_in[12]; const float* ab2 = (const float*)d_in[13];
  const float* aW3 = (const float*)d_in[14]; const float* ab3 = (const float*)d_in[15];
  const float* Wih_f = (const float*)d_in[16]; const float* Whh_f = (const float*)d_in[17];
  const float* bih_f = (const float*)d_in[18]; const float* bhh_f = (const float*)d_in[19];
  const float* Wih_r = (const float*)d_in[20]; const float* Whh_r = (const float*)d_in[21];
  const float* bih_r = (const float*)d_in[22]; const float* bhh_r = (const float*)d_in[23];
  const float* W3 = (const float*)d_in[24]; const float* b3 = (const float*)d_in[25];
  const float* g3 = (const float*)d_in[26]; const float* bt3 = (const float*)d_in[27];
  const float* W4 = (const float*)d_in[28]; const float* b4 = (const float*)d_in[29];
  const float* g4 = (const float*)d_in[30]; const float* bt4 = (const float*)d_in[31];
  float* out = (float*)d_out;

  // Workspace layout (float offsets). t_buf overlaps thB (dead before k_scan).
  float* ws = (float*)d_ws;
  float* Wih4f = ws;                  // 131072
  float* Wih4r = ws + 131072;         // 131072
  float* Whh4f = ws + 262144;         // 65536
  float* Whh4r = ws + 327680;         // 65536
  float* bsumf = ws + 393216;         // 512
  float* bsumr = ws + 393728;         // 512
  float* thB   = ws + 394240;         // 262144 (parity-1 thoughts buffer)
  float* t_buf = ws + 394240;         // overlap: used only before k_prep/k_scan
  int* ibase   = (int*)(ws + 656384);
  int* membi   = ibase;               // 16384
  int* reqi    = ibase + 16384;       // 16384
  int* isin    = ibase + 32768;       // 1024
  int* flag    = ibase + 33792;       // 64
  int* fin     = ibase + 33856;       // 1024
  int* lstart  = ibase + 34880;       // 1027 (pad to 1088)
  int* llist   = ibase + 35968;       // 1024
  int* bar     = ibase + 36992;       // 64
  size_t need = (size_t)(656384 + 37056 + 64) * 4;  // ~2.77 MB
  if (ws_size < need) return;  // diagnosable absmax-fail instead of a fault

  (void)in_sizes; (void)n_in; (void)out_size;

  float* thA = out;  // parity-0 thoughts buffer aliases d_out

  k_cdet<<<1, 64, 0, stream>>>(C, flag);
  k_actor1a<<<256, 256, 0, stream>>>(obs, W1, b1, g1, bt1, t_buf);
  k_actor1b<<<256, 256, 0, stream>>>(t_buf, W2, b2, g2, bt2, thA);
  k_att<<<256, 256, 0, stream>>>(thA, aW1, ab1, aW2, ab2, aW3, ab3, isin);
  k_memb<<<1024, 64, 0, stream>>>(C, flag, membi);
  k_req<<<1024, 256, 0, stream>>>(C, flag, membi, isin, reqi);
  k_prep<<<512, 256, 0, stream>>>(Wih_f, Wih_r, Whh_f, Whh_r, bih_f, bhh_f, bih_r, bhh_r,
                                  Wih4f, Wih4r, Whh4f, Whh4r, bsumf, bsumr, bar);
  k_lvl<<<1, 64, 0, stream>>>(isin, membi, fin, lstart, llist);
  k_scan<<<NWGC, 512, 0, stream>>>(thA, thB, lstart, llist, membi, reqi, bar,
                                   Wih4f, Wih4r, Whh4f, Whh4r, bsumf, bsumr);
  k_actor2<<<256, 256, 0, stream>>>(thA, thB, fin, W3, b3, g3, bt3, W4, b4, g4, bt4, out);
}

// Round 11
// 12863.625 us; speedup vs baseline: 1.7328x; 1.2264x over previous
//
#include <hip/hip_runtime.h>
#include <cstdint>
#include <cstddef>
#include <math.h>

#define A_N   1024
#define OBS_N 2048
#define TD_N  256
#define H_N   128
#define M_N   16
#define AE_N  64
#define NWGC  16   // k_scan grid: 16 WGs (8 parallel steps), 1 WG/CU (LDS-forced)

typedef _Float16 h2 __attribute__((ext_vector_type(2)));

__device__ __forceinline__ float sigf(float x) { return 1.0f / (1.0f + expf(-x)); }
__device__ __forceinline__ float dot4(float4 a, float4 b) {
  return a.x * b.x + a.y * b.y + a.z * b.z + a.w * b.w;
}
__device__ __forceinline__ h2 u2h(unsigned int u) { union { unsigned int x; h2 h; } c; c.x = u; return c.h; }
__device__ __forceinline__ unsigned int packh(float a, float b) {
  union { h2 h; unsigned int u; } c;
  c.h = (h2){(_Float16)a, (_Float16)b};
  return c.u;
}

// C may arrive as uint8 (1B/elem) or int32 (4B/elem). Detect on device.
__device__ __forceinline__ bool c_at(const unsigned char* C, int as_int, size_t idx) {
  return as_int ? (((const int*)C)[idx] != 0) : (C[idx] != 0);
}

__global__ __launch_bounds__(64) void k_cdet(const unsigned char* __restrict__ C, int* __restrict__ flag) {
  int lane = threadIdx.x;
  int cnt = 0;
  for (int i = lane; i < 4096; i += 64) cnt += (C[i] != 0) ? 1 : 0;
  for (int off = 32; off; off >>= 1) cnt += __shfl_down(cnt, off);
  if (lane == 0) flag[0] = (cnt < 40) ? 1 : 0;
}

// ---------------- k1: t = relu(LN(obs@W1 + b1)) ----------------
__global__ __launch_bounds__(256) void k_actor1a(const float* __restrict__ obs,
    const float* __restrict__ W1, const float* __restrict__ b1,
    const float* __restrict__ g1, const float* __restrict__ bt1,
    float* __restrict__ tout) {
  __shared__ float S[4 * OBS_N];
  __shared__ float red[4][4][2];
  int tid = threadIdx.x;
  int r0 = blockIdx.x * 4;
  {
    const float4* src = (const float4*)(obs + (size_t)r0 * OBS_N);
    float4* dst = (float4*)S;
    for (int i = tid; i < 4 * OBS_N / 4; i += 256) dst[i] = src[i];
  }
  __syncthreads();
  int j = tid;
  float acc0 = 0, acc1 = 0, acc2 = 0, acc3 = 0;
  const float4* S4 = (const float4*)S;
  for (int k4 = 0; k4 < OBS_N / 4; k4++) {
    float w0 = W1[(k4 * 4 + 0) * TD_N + j];
    float w1 = W1[(k4 * 4 + 1) * TD_N + j];
    float w2 = W1[(k4 * 4 + 2) * TD_N + j];
    float w3 = W1[(k4 * 4 + 3) * TD_N + j];
    float4 s0 = S4[0 * 512 + k4], s1 = S4[1 * 512 + k4], s2 = S4[2 * 512 + k4], s3 = S4[3 * 512 + k4];
    acc0 += s0.x * w0 + s0.y * w1 + s0.z * w2 + s0.w * w3;
    acc1 += s1.x * w0 + s1.y * w1 + s1.z * w2 + s1.w * w3;
    acc2 += s2.x * w0 + s2.y * w1 + s2.z * w2 + s2.w * w3;
    acc3 += s3.x * w0 + s3.y * w1 + s3.z * w2 + s3.w * w3;
  }
  float z[4] = {acc0 + b1[j], acc1 + b1[j], acc2 + b1[j], acc3 + b1[j]};
  int w = tid >> 6, lane = tid & 63;
  for (int r = 0; r < 4; r++) {
    float v = z[r], v2 = z[r] * z[r];
    for (int off = 32; off; off >>= 1) { v += __shfl_down(v, off); v2 += __shfl_down(v2, off); }
    if (lane == 0) { red[r][w][0] = v; red[r][w][1] = v2; }
  }
  __syncthreads();
  for (int r = 0; r < 4; r++) {
    float sm = red[r][0][0] + red[r][1][0] + red[r][2][0] + red[r][3][0];
    float sq = red[r][0][1] + red[r][1][1] + red[r][2][1] + red[r][3][1];
    float mean = sm * (1.0f / TD_N);
    float var = sq * (1.0f / TD_N) - mean * mean;
    float rs = 1.0f / sqrtf(var + 1e-5f);
    float val = (z[r] - mean) * rs * g1[j] + bt1[j];
    tout[(size_t)(r0 + r) * TD_N + j] = fmaxf(val, 0.0f);
  }
}

// ---------------- k2: thoughts = LN(t@W2 + b2) -> thA (= d_out) ----------------
__global__ __launch_bounds__(256) void k_actor1b(const float* __restrict__ tin,
    const float* __restrict__ W2, const float* __restrict__ b2,
    const float* __restrict__ g2, const float* __restrict__ bt2,
    float* __restrict__ th) {
  __shared__ float S[4 * TD_N];
  __shared__ float red[4][4][2];
  int tid = threadIdx.x;
  int r0 = blockIdx.x * 4;
  for (int i = tid; i < 4 * TD_N; i += 256) S[i] = tin[(size_t)r0 * TD_N + i];
  __syncthreads();
  int j = tid;
  float z[4] = {0, 0, 0, 0};
  const float4* S4 = (const float4*)S;
  for (int k4 = 0; k4 < TD_N / 4; k4++) {
    float w0 = W2[(k4 * 4 + 0) * TD_N + j];
    float w1 = W2[(k4 * 4 + 1) * TD_N + j];
    float w2v = W2[(k4 * 4 + 2) * TD_N + j];
    float w3 = W2[(k4 * 4 + 3) * TD_N + j];
#pragma unroll
    for (int r = 0; r < 4; r++) {
      float4 sv = S4[r * 64 + k4];
      z[r] += sv.x * w0 + sv.y * w1 + sv.z * w2v + sv.w * w3;
    }
  }
  for (int r = 0; r < 4; r++) z[r] += b2[j];
  int w = tid >> 6, lane = tid & 63;
  for (int r = 0; r < 4; r++) {
    float v = z[r], v2 = z[r] * z[r];
    for (int off = 32; off; off >>= 1) { v += __shfl_down(v, off); v2 += __shfl_down(v2, off); }
    if (lane == 0) { red[r][w][0] = v; red[r][w][1] = v2; }
  }
  __syncthreads();
  for (int r = 0; r < 4; r++) {
    float sm = red[r][0][0] + red[r][1][0] + red[r][2][0] + red[r][3][0];
    float sq = red[r][0][1] + red[r][1][1] + red[r][2][1] + red[r][3][1];
    float mean = sm * (1.0f / TD_N);
    float var = sq * (1.0f / TD_N) - mean * mean;
    float rs = 1.0f / sqrtf(var + 1e-5f);
    th[(size_t)(r0 + r) * TD_N + j] = (z[r] - mean) * rs * g2[j] + bt2[j];
  }
}

// ---------------- k3: attention unit -> is_init (fp64: x>0 decision is razor-thin) ----------------
__global__ __launch_bounds__(256) void k_att(const float* __restrict__ th,
    const float* __restrict__ aW1, const float* __restrict__ ab1,
    const float* __restrict__ aW2, const float* __restrict__ ab2,
    const float* __restrict__ aW3, const float* __restrict__ ab3,
    int* __restrict__ isin) {
  __shared__ float S[4 * TD_N];
  __shared__ double A1[4 * AE_N];
  __shared__ double A2[4 * AE_N];
  int tid = threadIdx.x;
  int r0 = blockIdx.x * 4;
  for (int i = tid; i < 4 * TD_N; i += 256) S[i] = th[(size_t)r0 * TD_N + i];
  __syncthreads();
  int r = tid >> 6, c = tid & 63;
  double acc = 0;
  for (int k = 0; k < TD_N; k++) acc += (double)S[r * TD_N + k] * (double)aW1[k * AE_N + c];
  acc += (double)ab1[c];
  A1[r * AE_N + c] = acc > 0.0 ? acc : 0.0;
  __syncthreads();
  acc = 0;
  for (int k = 0; k < AE_N; k++) acc += A1[r * AE_N + k] * (double)aW2[k * AE_N + c];
  acc += (double)ab2[c];
  A2[r * AE_N + c] = acc > 0.0 ? acc : 0.0;
  __syncthreads();
  double p = A2[r * AE_N + c] * (double)aW3[c];
  for (int off = 32; off; off >>= 1) p += __shfl_down(p, off);
  if (c == 0) isin[r0 + r] = ((p + (double)ab3[0]) > 0.0) ? 1 : 0;
}

// ---------------- k_memb: member indices (ascending) per row ----------------
__global__ __launch_bounds__(64) void k_memb(const unsigned char* __restrict__ C,
    const int* __restrict__ flag, int* __restrict__ memb) {
  int s = blockIdx.x, lane = threadIdx.x;
  int as_int = flag[0];
  if (lane < M_N) memb[s * M_N + lane] = lane;  // safe defaults (never poison)
  __syncthreads();
  int base = 0;
  for (int ch = 0; ch < 16; ch++) {
    int col = ch * 64 + lane;
    bool v = c_at(C, as_int, (size_t)s * A_N + col);
    unsigned long long m = __ballot(v);
    if (v) {
      int pos = base + __popcll(m & ((1ull << lane) - 1ull));
      if (pos < M_N) memb[s * M_N + pos] = col;
    }
    base += __popcll(m);
  }
}

// ---------------- k_req: write ordinal per (step, member slot) ----------------
__global__ __launch_bounds__(256) void k_req(const unsigned char* __restrict__ C,
    const int* __restrict__ flag, const int* __restrict__ memb,
    const int* __restrict__ isin, int* __restrict__ req) {
  __shared__ int Ls[A_N];
  int s = blockIdx.x, tid = threadIdx.x;
  int as_int = flag[0];
  for (int i = tid; i < A_N; i += 256) Ls[i] = isin[i];
  __syncthreads();
  int i = tid >> 4, sub = tid & 15;
  int m = memb[s * M_N + i] & (A_N - 1);
  int cnt = 0;
  for (int s2 = sub; s2 < s; s2 += 16)
    if (Ls[s2] && c_at(C, as_int, (size_t)s2 * A_N + m)) cnt++;
  for (int off = 1; off < 16; off <<= 1) cnt += __shfl_xor(cnt, off);
  if (sub == 0) req[s * M_N + i] = cnt;
}

// ---------------- k_prep: weight re-layouts, bias sums, bar reset ----------------
// Wih4 fp32 k-major (as R10): Wih4[(k4*512+g)*4+kk] = Wih[g*256 + k4*4 + kk]
// Whh packed fp16 pairs: whhp[k2*512+g] = half2(Whh[g][2k2], Whh[g][2k2+1]), k2 in [0,64)
__global__ __launch_bounds__(256) void k_prep(
    const float* __restrict__ Wih_f, const float* __restrict__ Wih_r,
    const float* __restrict__ Whh_f, const float* __restrict__ Whh_r,
    const float* __restrict__ bih_f, const float* __restrict__ bhh_f,
    const float* __restrict__ bih_r, const float* __restrict__ bhh_r,
    float* __restrict__ Wih4f, float* __restrict__ Wih4r,
    unsigned int* __restrict__ whhpf, unsigned int* __restrict__ whhpr,
    float* __restrict__ bsumf, float* __restrict__ bsumr, int* __restrict__ bar) {
  int id = blockIdx.x * 256 + threadIdx.x;  // 512*256 = 131072
  {
    int kk = id & 3, g = (id >> 2) & 511, k4 = id >> 11;
    Wih4f[id] = Wih_f[g * TD_N + k4 * 4 + kk];
    Wih4r[id] = Wih_r[g * TD_N + k4 * 4 + kk];
  }
  if (id < 32768) {
    int g = id & 511, k2 = id >> 9;
    whhpf[id] = packh(Whh_f[g * H_N + 2 * k2], Whh_f[g * H_N + 2 * k2 + 1]);
    whhpr[id] = packh(Whh_r[g * H_N + 2 * k2], Whh_r[g * H_N + 2 * k2 + 1]);
  }
  if (id < 512) { bsumf[id] = bih_f[id] + bhh_f[id]; bsumr[id] = bih_r[id] + bhh_r[id]; }
  if (id == 0) bar[0] = 0;
}

// ---------------- k_lvl: topological levels; single wave, fully LDS-resident ----------------
__global__ __launch_bounds__(64) void k_lvl(const int* __restrict__ isin,
    const int* __restrict__ memb, int* __restrict__ fin,
    int* __restrict__ lstart, int* __restrict__ llist) {
  __shared__ int membS[A_N * M_N];        // 64 KB
  __shared__ int last[A_N];               // 4 KB
  __shared__ int cnt[A_N + 2];            // 4 KB
  __shared__ int cur[A_N + 2];            // 4 KB
  __shared__ short lvlS[A_N];             // 2 KB
  __shared__ unsigned char isinS[A_N];    // 1 KB
  __shared__ unsigned char cntm[A_N];     // 1 KB
  int lane = threadIdx.x;
  for (int i = lane; i < A_N * M_N; i += 64) membS[i] = memb[i] & (A_N - 1);
  for (int i = lane; i < A_N; i += 64) {
    isinS[i] = (unsigned char)(isin[i] != 0);
    last[i] = 0; cntm[i] = 0; lvlS[i] = 0;
  }
  for (int l = lane; l < A_N + 2; l += 64) cnt[l] = 0;
  __syncthreads();
  int lmax = 0;
  for (int s = 0; s < A_N; s++) {
    if (isinS[s]) {             // uniform branch (LDS broadcast)
      int li = 0, m = 0;
      if (lane < 16) { m = membS[s * M_N + lane]; li = last[m]; }
#pragma unroll
      for (int off = 8; off; off >>= 1) li = max(li, __shfl_xor(li, off));
      int L = __shfl(li, 0) + 1;
      if (lane < 16) { last[m] = L; cntm[m]++; }
      if (lane == 0) { lvlS[s] = (short)L; cnt[L]++; }
      lmax = max(lmax, L);
    }
  }
  if (lane == 0) {
    int acc = 0;
    for (int L = 1; L <= A_N + 1; L++) {
      cur[L] = acc; lstart[L] = acc;
      if (L <= A_N) acc += cnt[L];
    }
    lstart[0] = lmax;
    for (int s = 0; s < A_N; s++) {
      int L = lvlS[s];
      if (L > 0) llist[cur[L]++] = s;
    }
  }
  for (int i = lane; i < A_N; i += 64) fin[i] = cntm[i] & 1;
}

// ---------------- k_scan: single-dispatch level-parallel scan ----------------
// 16 WGs x 512 threads, 2 WGs per step (one per dir). Thread tid owns gate
// column tid of its dir. Whh column held in registers as PACKED FP16:
// 64 x uint (half2) = 64 VGPRs -- fits the 128-VGPR budget the toolchain
// grants 512-thread WGs (fp32 version = 128 VGPRs never fit: R5-R10).
// Recurrence: v_dot2_f32_f16 (fp16 mul, FP32 ACCUMULATE) against h packed
// to fp16 per timestep. |w|~0.02 -> fp16 weight error ~1e-5 abs: negligible.
// LDS pad forces 1 WG/CU (else allocator targets 2 WG/CU and caps VGPR=64).
#define SPAD 16384  // LDS pad (floats): total ~82.8 KB > 160/2
__global__ __launch_bounds__(512)
void k_scan(
    float* __restrict__ thA, float* __restrict__ thB,
    const int* __restrict__ lstart, const int* __restrict__ llist,
    const int* __restrict__ memb, const int* __restrict__ req, int* __restrict__ bar,
    const float* __restrict__ Wih4f, const float* __restrict__ Wih4r,
    const unsigned int* __restrict__ whhpf, const unsigned int* __restrict__ whhpr,
    const float* __restrict__ bsumf, const float* __restrict__ bsumr) {
  __shared__ float S[16 * TD_N + SPAD];  // 16 KB used + 64 KB occupancy pad
  __shared__ float garr[4 * H_N];        // gates i,f,g,o 2 KB
  __shared__ unsigned int hp[2 * 64];    // packed fp16 h, ping-pong, 512 B
  __shared__ int memb_s[16];
  __shared__ int par_s[16];
  int tid = threadIdx.x;
  int wg = blockIdx.x;
  int dir = wg & 1;
  int dmask = dir ? 15 : 0;
  const float4* Wih4 = (const float4*)(dir ? Wih4r : Wih4f);
  const unsigned int* whhp = dir ? whhpr : whhpf;
  float blo = (dir ? bsumr : bsumf)[tid];
  int istanh = ((tid >> 7) == 2);  // gate order i,f,g,o; g-chunk uses tanh
  // Whh column in registers, packed fp16: 64 VGPRs, asm-pinned against remat
  unsigned int wreg[64];
#pragma unroll
  for (int k2 = 0; k2 < 64; k2++) wreg[k2] = whhp[k2 * 512 + tid];
#pragma unroll
  for (int k2 = 0; k2 < 64; k2++) asm volatile("" : "+v"(wreg[k2]));

  int lmax = lstart[0];
  int round = 0;
  for (int L = 1; L <= lmax; L++) {
    int i0 = lstart[L], i1 = lstart[L + 1];
    for (int pi = wg >> 1; pi < i1 - i0; pi += NWGC >> 1) {
      int s = llist[i0 + pi];
      if (tid < 16) { memb_s[tid] = memb[s * M_N + tid] & (A_N - 1); par_s[tid] = req[s * M_N + tid] & 1; }
      __syncthreads();
      {  // gather 16 member rows (coherent L3 loads); conflict-free q*32+p layout
        int r = tid >> 5, p = tid & 31;
        const float* src = (par_s[r] ? thB : thA) + (size_t)memb_s[r] * TD_N;
        float* dst = S + r * TD_N;
#pragma unroll
        for (int q = 0; q < 8; q++)
          dst[q * 32 + p] = __hip_atomic_load(src + q * 32 + p, __ATOMIC_RELAXED, __HIP_MEMORY_SCOPE_AGENT);
      }
      __syncthreads();
      // ---- input transform (fp32): xa[t] = bsum + seq[t] . Wih[:,tid]
      float xa[16];
#pragma unroll
      for (int t = 0; t < 16; t++) xa[t] = blo;
      {
        const float4* S4 = (const float4*)S;
#pragma unroll 2
        for (int k4 = 0; k4 < 64; k4++) {
          float4 wv = Wih4[k4 * 512 + tid];
#pragma unroll
          for (int t = 0; t < 16; t++) {
            float4 sv = S4[(t ^ dmask) * 64 + k4];
            xa[t] += dot4(sv, wv);
          }
        }
      }
      if (tid < 64) hp[tid] = 0u;  // h0 = 0 (packed), buf 0
      float cst = 0.0f;
      __syncthreads();
      // ---- recurrence, fully unrolled; weights from pinned fp16 registers
#pragma unroll
      for (int u = 0; u < 16; u++) {
        const uint4* hp4 = (const uint4*)(hp + (u & 1) * 64);
        float z0 = 0, z1 = 0, z2 = 0, z3 = 0;
#pragma unroll
        for (int j = 0; j < 16; j++) {
          uint4 hw = hp4[j];  // broadcast read (all lanes same addr)
          z0 = __builtin_amdgcn_fdot2(u2h(wreg[4 * j + 0]), u2h(hw.x), z0, false);
          z1 = __builtin_amdgcn_fdot2(u2h(wreg[4 * j + 1]), u2h(hw.y), z1, false);
          z2 = __builtin_amdgcn_fdot2(u2h(wreg[4 * j + 2]), u2h(hw.z), z2, false);
          z3 = __builtin_amdgcn_fdot2(u2h(wreg[4 * j + 3]), u2h(hw.w), z3, false);
        }
        float z = xa[u] + (z0 + z1) + (z2 + z3);
        garr[tid] = istanh ? tanhf(z) : sigf(z);
        __syncthreads();
        if (tid < H_N) {
          cst = garr[H_N + tid] * cst + garr[tid] * garr[2 * H_N + tid];
          float hv = garr[3 * H_N + tid] * tanhf(cst);
          // pack pair (2t, 2t+1) -> hp word t via shfl (pairs are wave-local)
          float hvn = __shfl_down(hv, 1);
          if (!(tid & 1)) hp[((u + 1) & 1) * 64 + (tid >> 1)] = packh(hv, hvn);
          int r2 = u ^ dmask;                 // fwd: u; bwd: 15-u (rev-aligned)
          float* dst = par_s[r2] ? thA : thB; // write opposite parity buffer
          __hip_atomic_store(dst + (size_t)memb_s[r2] * TD_N + dir * H_N + tid, hv,
                             __ATOMIC_RELAXED, __HIP_MEMORY_SCOPE_AGENT);
        }
        __syncthreads();
      }
    }
    // ---- grid barrier: syncthreads (drains vmcnt for all threads) + relaxed add/poll
    round++;
    __syncthreads();
    if (tid == 0) {
      __hip_atomic_fetch_add(bar, 1, __ATOMIC_RELAXED, __HIP_MEMORY_SCOPE_AGENT);
      int target = round * NWGC;
      int tries = 0;
      while (__hip_atomic_load(bar, __ATOMIC_RELAXED, __HIP_MEMORY_SCOPE_AGENT) < target) {
        __builtin_amdgcn_s_sleep(1);
        if (++tries > (1 << 17)) break;  // failsafe: wrong-answer beats hang
      }
    }
    __syncthreads();
  }
}

// ---------------- k_actor2: acts = tanh(LN(LN(relu(th)@W3+b3)@W4+b4)) ----------------
__global__ __launch_bounds__(256) void k_actor2(const float* __restrict__ thA, const float* __restrict__ thB,
    const int* __restrict__ fin,
    const float* __restrict__ W3, const float* __restrict__ b3,
    const float* __restrict__ g3, const float* __restrict__ bt3,
    const float* __restrict__ W4, const float* __restrict__ b4,
    const float* __restrict__ g4, const float* __restrict__ bt4,
    float* __restrict__ out) {
  __shared__ float Hs[4 * TD_N];
  __shared__ float H3[4 * TD_N];
  __shared__ float red[4][4][2];
  int tid = threadIdx.x;
  int r0 = blockIdx.x * 4;
  int j = tid;
  for (int i = tid; i < 4 * TD_N; i += 256) {
    int r = i >> 8, col = i & 255;
    int row = r0 + r;
    const float* src = (fin[row] ? thB : thA) + (size_t)row * TD_N + col;
    float v = __hip_atomic_load(src, __ATOMIC_RELAXED, __HIP_MEMORY_SCOPE_AGENT);
    Hs[i] = fmaxf(v, 0.0f);
  }
  __syncthreads();  // all reads of own rows complete before any write below
  float z[4] = {0, 0, 0, 0};
  {
    const float4* S4 = (const float4*)Hs;
    for (int k4 = 0; k4 < 64; k4++) {
      float w0 = W3[(k4 * 4 + 0) * TD_N + j];
      float w1 = W3[(k4 * 4 + 1) * TD_N + j];
      float w2 = W3[(k4 * 4 + 2) * TD_N + j];
      float w3v = W3[(k4 * 4 + 3) * TD_N + j];
#pragma unroll
      for (int r = 0; r < 4; r++) {
        float4 sv = S4[r * 64 + k4];
        z[r] += sv.x * w0 + sv.y * w1 + sv.z * w2 + sv.w * w3v;
      }
    }
  }
  for (int r = 0; r < 4; r++) z[r] += b3[j];
  int w = tid >> 6, lane = tid & 63;
  for (int r = 0; r < 4; r++) {
    float v = z[r], v2 = z[r] * z[r];
    for (int off = 32; off; off >>= 1) { v += __shfl_down(v, off); v2 += __shfl_down(v2, off); }
    if (lane == 0) { red[r][w][0] = v; red[r][w][1] = v2; }
  }
  __syncthreads();
  for (int r = 0; r < 4; r++) {
    float sm = red[r][0][0] + red[r][1][0] + red[r][2][0] + red[r][3][0];
    float sq = red[r][0][1] + red[r][1][1] + red[r][2][1] + red[r][3][1];
    float mean = sm * (1.0f / TD_N);
    float var = sq * (1.0f / TD_N) - mean * mean;
    float rs = 1.0f / sqrtf(var + 1e-5f);
    H3[r * TD_N + j] = (z[r] - mean) * rs * g3[j] + bt3[j];
  }
  __syncthreads();
  float z2a[4] = {0, 0, 0, 0};
  {
    const float4* S4 = (const float4*)H3;
    for (int k4 = 0; k4 < 64; k4++) {
      float w0 = W4[(k4 * 4 + 0) * TD_N + j];
      float w1 = W4[(k4 * 4 + 1) * TD_N + j];
      float w2 = W4[(k4 * 4 + 2) * TD_N + j];
      float w3v = W4[(k4 * 4 + 3) * TD_N + j];
#pragma unroll
      for (int r = 0; r < 4; r++) {
        float4 sv = S4[r * 64 + k4];
        z2a[r] += sv.x * w0 + sv.y * w1 + sv.z * w2 + sv.w * w3v;
      }
    }
  }
  for (int r = 0; r < 4; r++) z2a[r] += b4[j];
  __syncthreads();
  for (int r = 0; r < 4; r++) {
    float v = z2a[r], v2 = z2a[r] * z2a[r];
    for (int off = 32; off; off >>= 1) { v += __shfl_down(v, off); v2 += __shfl_down(v2, off); }
    if (lane == 0) { red[r][w][0] = v; red[r][w][1] = v2; }
  }
  __syncthreads();
  for (int r = 0; r < 4; r++) {
    float sm = red[r][0][0] + red[r][1][0] + red[r][2][0] + red[r][3][0];
    float sq = red[r][0][1] + red[r][1][1] + red[r][2][1] + red[r][3][1];
    float mean = sm * (1.0f / TD_N);
    float var = sq * (1.0f / TD_N) - mean * mean;
    float rs = 1.0f / sqrtf(var + 1e-5f);
    float val = (z2a[r] - mean) * rs * g4[j] + bt4[j];
    out[(size_t)(r0 + r) * TD_N + j] = tanhf(val);
  }
}

extern "C" void kernel_launch(void* const* d_in, const int* in_sizes, int n_in,
                              void* d_out, int out_size, void* d_ws, size_t ws_size,
                              hipStream_t stream) {
  const float* obs = (const float*)d_in[0];
  const unsigned char* C = (const unsigned char*)d_in[1];
  const float* W1 = (const float*)d_in[2];  const float* b1 = (const float*)d_in[3];
  const float* g1 = (const float*)d_in[4];  const float* bt1 = (const float*)d_in[5];
  const float* W2 = (const float*)d_in[6];  const float* b2 = (const float*)d_in[7];
  const float* g2 = (const float*)d_in[8];  const float* bt2 = (const float*)d_in[9];
  const float* aW1 = (const float*)d_in[10]; const float* ab1 = (const float*)d_in[11];
  const float* aW2 = (const float*)d_in[12]; const float* ab2 = (const float*)d_in[13];
  const float* aW3 = (const float*)d_in[14]; const float* ab3 = (const float*)d_in[15];
  const float* Wih_f = (const float*)d_in[16]; const float* Whh_f = (const float*)d_in[17];
  const float* bih_f = (const float*)d_in[18]; const float* bhh_f = (const float*)d_in[19];
  const float* Wih_r = (const float*)d_in[20]; const float* Whh_r = (const float*)d_in[21];
  const float* bih_r = (const float*)d_in[22]; const float* bhh_r = (const float*)d_in[23];
  const float* W3 = (const float*)d_in[24]; const float* b3 = (const float*)d_in[25];
  const float* g3 = (const float*)d_in[26]; const float* bt3 = (const float*)d_in[27];
  const float* W4 = (const float*)d_in[28]; const float* b4 = (const float*)d_in[29];
  const float* g4 = (const float*)d_in[30]; const float* bt4 = (const float*)d_in[31];
  float* out = (float*)d_out;

  // Workspace layout (float offsets). t_buf overlaps thB (dead before k_scan).
  float* ws = (float*)d_ws;
  float* Wih4f = ws;                  // 131072
  float* Wih4r = ws + 131072;         // 131072
  unsigned int* whhpf = (unsigned int*)(ws + 262144);  // 32768 u32
  unsigned int* whhpr = (unsigned int*)(ws + 327680);  // 32768 u32
  float* bsumf = ws + 393216;         // 512
  float* bsumr = ws + 393728;         // 512
  float* thB   = ws + 394240;         // 262144 (parity-1 thoughts buffer)
  float* t_buf = ws + 394240;         // overlap: used only before k_prep/k_scan
  int* ibase   = (int*)(ws + 656384);
  int* membi   = ibase;               // 16384
  int* reqi    = ibase + 16384;       // 16384
  int* isin    = ibase + 32768;       // 1024
  int* flag    = ibase + 33792;       // 64
  int* fin     = ibase + 33856;       // 1024
  int* lstart  = ibase + 34880;       // 1027 (pad to 1088)
  int* llist   = ibase + 35968;       // 1024
  int* bar     = ibase + 36992;       // 64
  size_t need = (size_t)(656384 + 37056 + 64) * 4;  // ~2.77 MB
  if (ws_size < need) return;  // diagnosable absmax-fail instead of a fault

  (void)in_sizes; (void)n_in; (void)out_size;

  float* thA = out;  // parity-0 thoughts buffer aliases d_out

  k_cdet<<<1, 64, 0, stream>>>(C, flag);
  k_actor1a<<<256, 256, 0, stream>>>(obs, W1, b1, g1, bt1, t_buf);
  k_actor1b<<<256, 256, 0, stream>>>(t_buf, W2, b2, g2, bt2, thA);
  k_att<<<256, 256, 0, stream>>>(thA, aW1, ab1, aW2, ab2, aW3, ab3, isin);
  k_memb<<<1024, 64, 0, stream>>>(C, flag, membi);
  k_req<<<1024, 256, 0, stream>>>(C, flag, membi, isin, reqi);
  k_prep<<<512, 256, 0, stream>>>(Wih_f, Wih_r, Whh_f, Whh_r, bih_f, bhh_f, bih_r, bhh_r,
                                  Wih4f, Wih4r, whhpf, whhpr, bsumf, bsumr, bar);
  k_lvl<<<1, 64, 0, stream>>>(isin, membi, fin, lstart, llist);
  k_scan<<<NWGC, 512, 0, stream>>>(thA, thB, lstart, llist, membi, reqi, bar,
                                   Wih4f, Wih4r, whhpf, whhpr, bsumf, bsumr);
  k_actor2<<<256, 256, 0, stream>>>(thA, thB, fin, W3, b3, g3, bt3, W4, b4, g4, bt4, out);
}

// Round 12
// 12625.064 us; speedup vs baseline: 1.7656x; 1.0189x over previous
//
#include <hip/hip_runtime.h>
#include <cstdint>
#include <cstddef>
#include <math.h>

#define A_N   1024
#define OBS_N 2048
#define TD_N  256
#define H_N   128
#define M_N   16
#define AE_N  64
#define NWGC  16   // k_scan grid: 16 WGs (8 step-pairs), 1 WG/CU (LDS-forced)

typedef _Float16 h2 __attribute__((ext_vector_type(2)));

__device__ __forceinline__ float sigf(float x) { return 1.0f / (1.0f + expf(-x)); }
__device__ __forceinline__ float dot4(float4 a, float4 b) {
  return a.x * b.x + a.y * b.y + a.z * b.z + a.w * b.w;
}
__device__ __forceinline__ h2 u2h(unsigned int u) { union { unsigned int x; h2 h; } c; c.x = u; return c.h; }
__device__ __forceinline__ unsigned int packh(float a, float b) {
  union { h2 h; unsigned int u; } c;
  c.h = (h2){(_Float16)a, (_Float16)b};
  return c.u;
}

// C may arrive as uint8 (1B/elem) or int32 (4B/elem). Detect on device.
__device__ __forceinline__ bool c_at(const unsigned char* C, int as_int, size_t idx) {
  return as_int ? (((const int*)C)[idx] != 0) : (C[idx] != 0);
}

__global__ __launch_bounds__(64) void k_cdet(const unsigned char* __restrict__ C, int* __restrict__ flag) {
  int lane = threadIdx.x;
  int cnt = 0;
  for (int i = lane; i < 4096; i += 64) cnt += (C[i] != 0) ? 1 : 0;
  for (int off = 32; off; off >>= 1) cnt += __shfl_down(cnt, off);
  if (lane == 0) flag[0] = (cnt < 40) ? 1 : 0;
}

// ---------------- k1: t = relu(LN(obs@W1 + b1)) ----------------
__global__ __launch_bounds__(256) void k_actor1a(const float* __restrict__ obs,
    const float* __restrict__ W1, const float* __restrict__ b1,
    const float* __restrict__ g1, const float* __restrict__ bt1,
    float* __restrict__ tout) {
  __shared__ float S[4 * OBS_N];
  __shared__ float red[4][4][2];
  int tid = threadIdx.x;
  int r0 = blockIdx.x * 4;
  {
    const float4* src = (const float4*)(obs + (size_t)r0 * OBS_N);
    float4* dst = (float4*)S;
    for (int i = tid; i < 4 * OBS_N / 4; i += 256) dst[i] = src[i];
  }
  __syncthreads();
  int j = tid;
  float acc0 = 0, acc1 = 0, acc2 = 0, acc3 = 0;
  const float4* S4 = (const float4*)S;
  for (int k4 = 0; k4 < OBS_N / 4; k4++) {
    float w0 = W1[(k4 * 4 + 0) * TD_N + j];
    float w1 = W1[(k4 * 4 + 1) * TD_N + j];
    float w2 = W1[(k4 * 4 + 2) * TD_N + j];
    float w3 = W1[(k4 * 4 + 3) * TD_N + j];
    float4 s0 = S4[0 * 512 + k4], s1 = S4[1 * 512 + k4], s2 = S4[2 * 512 + k4], s3 = S4[3 * 512 + k4];
    acc0 += s0.x * w0 + s0.y * w1 + s0.z * w2 + s0.w * w3;
    acc1 += s1.x * w0 + s1.y * w1 + s1.z * w2 + s1.w * w3;
    acc2 += s2.x * w0 + s2.y * w1 + s2.z * w2 + s2.w * w3;
    acc3 += s3.x * w0 + s3.y * w1 + s3.z * w2 + s3.w * w3;
  }
  float z[4] = {acc0 + b1[j], acc1 + b1[j], acc2 + b1[j], acc3 + b1[j]};
  int w = tid >> 6, lane = tid & 63;
  for (int r = 0; r < 4; r++) {
    float v = z[r], v2 = z[r] * z[r];
    for (int off = 32; off; off >>= 1) { v += __shfl_down(v, off); v2 += __shfl_down(v2, off); }
    if (lane == 0) { red[r][w][0] = v; red[r][w][1] = v2; }
  }
  __syncthreads();
  for (int r = 0; r < 4; r++) {
    float sm = red[r][0][0] + red[r][1][0] + red[r][2][0] + red[r][3][0];
    float sq = red[r][0][1] + red[r][1][1] + red[r][2][1] + red[r][3][1];
    float mean = sm * (1.0f / TD_N);
    float var = sq * (1.0f / TD_N) - mean * mean;
    float rs = 1.0f / sqrtf(var + 1e-5f);
    float val = (z[r] - mean) * rs * g1[j] + bt1[j];
    tout[(size_t)(r0 + r) * TD_N + j] = fmaxf(val, 0.0f);
  }
}

// ---------------- k2: thoughts = LN(t@W2 + b2) -> thA (= d_out) ----------------
__global__ __launch_bounds__(256) void k_actor1b(const float* __restrict__ tin,
    const float* __restrict__ W2, const float* __restrict__ b2,
    const float* __restrict__ g2, const float* __restrict__ bt2,
    float* __restrict__ th) {
  __shared__ float S[4 * TD_N];
  __shared__ float red[4][4][2];
  int tid = threadIdx.x;
  int r0 = blockIdx.x * 4;
  for (int i = tid; i < 4 * TD_N; i += 256) S[i] = tin[(size_t)r0 * TD_N + i];
  __syncthreads();
  int j = tid;
  float z[4] = {0, 0, 0, 0};
  const float4* S4 = (const float4*)S;
  for (int k4 = 0; k4 < TD_N / 4; k4++) {
    float w0 = W2[(k4 * 4 + 0) * TD_N + j];
    float w1 = W2[(k4 * 4 + 1) * TD_N + j];
    float w2v = W2[(k4 * 4 + 2) * TD_N + j];
    float w3 = W2[(k4 * 4 + 3) * TD_N + j];
#pragma unroll
    for (int r = 0; r < 4; r++) {
      float4 sv = S4[r * 64 + k4];
      z[r] += sv.x * w0 + sv.y * w1 + sv.z * w2v + sv.w * w3;
    }
  }
  for (int r = 0; r < 4; r++) z[r] += b2[j];
  int w = tid >> 6, lane = tid & 63;
  for (int r = 0; r < 4; r++) {
    float v = z[r], v2 = z[r] * z[r];
    for (int off = 32; off; off >>= 1) { v += __shfl_down(v, off); v2 += __shfl_down(v2, off); }
    if (lane == 0) { red[r][w][0] = v; red[r][w][1] = v2; }
  }
  __syncthreads();
  for (int r = 0; r < 4; r++) {
    float sm = red[r][0][0] + red[r][1][0] + red[r][2][0] + red[r][3][0];
    float sq = red[r][0][1] + red[r][1][1] + red[r][2][1] + red[r][3][1];
    float mean = sm * (1.0f / TD_N);
    float var = sq * (1.0f / TD_N) - mean * mean;
    float rs = 1.0f / sqrtf(var + 1e-5f);
    th[(size_t)(r0 + r) * TD_N + j] = (z[r] - mean) * rs * g2[j] + bt2[j];
  }
}

// ---------------- k3: attention unit -> is_init (fp64: x>0 decision is razor-thin) ----------------
__global__ __launch_bounds__(256) void k_att(const float* __restrict__ th,
    const float* __restrict__ aW1, const float* __restrict__ ab1,
    const float* __restrict__ aW2, const float* __restrict__ ab2,
    const float* __restrict__ aW3, const float* __restrict__ ab3,
    int* __restrict__ isin) {
  __shared__ float S[4 * TD_N];
  __shared__ double A1[4 * AE_N];
  __shared__ double A2[4 * AE_N];
  int tid = threadIdx.x;
  int r0 = blockIdx.x * 4;
  for (int i = tid; i < 4 * TD_N; i += 256) S[i] = th[(size_t)r0 * TD_N + i];
  __syncthreads();
  int r = tid >> 6, c = tid & 63;
  double acc = 0;
  for (int k = 0; k < TD_N; k++) acc += (double)S[r * TD_N + k] * (double)aW1[k * AE_N + c];
  acc += (double)ab1[c];
  A1[r * AE_N + c] = acc > 0.0 ? acc : 0.0;
  __syncthreads();
  acc = 0;
  for (int k = 0; k < AE_N; k++) acc += A1[r * AE_N + k] * (double)aW2[k * AE_N + c];
  acc += (double)ab2[c];
  A2[r * AE_N + c] = acc > 0.0 ? acc : 0.0;
  __syncthreads();
  double p = A2[r * AE_N + c] * (double)aW3[c];
  for (int off = 32; off; off >>= 1) p += __shfl_down(p, off);
  if (c == 0) isin[r0 + r] = ((p + (double)ab3[0]) > 0.0) ? 1 : 0;
}

// ---------------- k_memb: member indices (ascending) per row ----------------
__global__ __launch_bounds__(64) void k_memb(const unsigned char* __restrict__ C,
    const int* __restrict__ flag, int* __restrict__ memb) {
  int s = blockIdx.x, lane = threadIdx.x;
  int as_int = flag[0];
  if (lane < M_N) memb[s * M_N + lane] = lane;  // safe defaults (never poison)
  __syncthreads();
  int base = 0;
  for (int ch = 0; ch < 16; ch++) {
    int col = ch * 64 + lane;
    bool v = c_at(C, as_int, (size_t)s * A_N + col);
    unsigned long long m = __ballot(v);
    if (v) {
      int pos = base + __popcll(m & ((1ull << lane) - 1ull));
      if (pos < M_N) memb[s * M_N + pos] = col;
    }
    base += __popcll(m);
  }
}

// ---------------- k_req: write ordinal per (step, member slot) ----------------
__global__ __launch_bounds__(256) void k_req(const unsigned char* __restrict__ C,
    const int* __restrict__ flag, const int* __restrict__ memb,
    const int* __restrict__ isin, int* __restrict__ req) {
  __shared__ int Ls[A_N];
  int s = blockIdx.x, tid = threadIdx.x;
  int as_int = flag[0];
  for (int i = tid; i < A_N; i += 256) Ls[i] = isin[i];
  __syncthreads();
  int i = tid >> 4, sub = tid & 15;
  int m = memb[s * M_N + i] & (A_N - 1);
  int cnt = 0;
  for (int s2 = sub; s2 < s; s2 += 16)
    if (Ls[s2] && c_at(C, as_int, (size_t)s2 * A_N + m)) cnt++;
  for (int off = 1; off < 16; off <<= 1) cnt += __shfl_xor(cnt, off);
  if (sub == 0) req[s * M_N + i] = cnt;
}

// ---------------- k_prep: weight re-layouts, bias sums, version-counter reset ----------------
// Wih4 fp32 k-major: Wih4[(k4*512+g)*4+kk] = Wih[g*256 + k4*4 + kk]
// Whh packed fp16 pairs: whhp[k2*512+g] = half2(Whh[g][2k2], Whh[g][2k2+1])
__global__ __launch_bounds__(256) void k_prep(
    const float* __restrict__ Wih_f, const float* __restrict__ Wih_r,
    const float* __restrict__ Whh_f, const float* __restrict__ Whh_r,
    const float* __restrict__ bih_f, const float* __restrict__ bhh_f,
    const float* __restrict__ bih_r, const float* __restrict__ bhh_r,
    float* __restrict__ Wih4f, float* __restrict__ Wih4r,
    unsigned int* __restrict__ whhpf, unsigned int* __restrict__ whhpr,
    float* __restrict__ bsumf, float* __restrict__ bsumr,
    int* __restrict__ verF, int* __restrict__ verB) {
  int id = blockIdx.x * 256 + threadIdx.x;  // 512*256 = 131072
  {
    int kk = id & 3, g = (id >> 2) & 511, k4 = id >> 11;
    Wih4f[id] = Wih_f[g * TD_N + k4 * 4 + kk];
    Wih4r[id] = Wih_r[g * TD_N + k4 * 4 + kk];
  }
  if (id < 32768) {
    int g = id & 511, k2 = id >> 9;
    whhpf[id] = packh(Whh_f[g * H_N + 2 * k2], Whh_f[g * H_N + 2 * k2 + 1]);
    whhpr[id] = packh(Whh_r[g * H_N + 2 * k2], Whh_r[g * H_N + 2 * k2 + 1]);
  }
  if (id < 512) { bsumf[id] = bih_f[id] + bhh_f[id]; bsumr[id] = bih_r[id] + bhh_r[id]; }
  if (id < A_N) { verF[id] = 0; verB[id] = 0; }
}

// ---------------- k_lvl: level-sorted active-step list (single wave, LDS-resident) ----------------
// Output: lstart[0] = nact; llist[0..nact) = active steps sorted by topo level.
__global__ __launch_bounds__(64) void k_lvl(const int* __restrict__ isin,
    const int* __restrict__ memb, int* __restrict__ fin,
    int* __restrict__ lstart, int* __restrict__ llist) {
  __shared__ int membS[A_N * M_N];        // 64 KB
  __shared__ int last[A_N];               // 4 KB
  __shared__ int cnt[A_N + 2];            // 4 KB
  __shared__ int cur[A_N + 2];            // 4 KB
  __shared__ short lvlS[A_N];             // 2 KB
  __shared__ unsigned char isinS[A_N];    // 1 KB
  __shared__ unsigned char cntm[A_N];     // 1 KB
  int lane = threadIdx.x;
  for (int i = lane; i < A_N * M_N; i += 64) membS[i] = memb[i] & (A_N - 1);
  for (int i = lane; i < A_N; i += 64) {
    isinS[i] = (unsigned char)(isin[i] != 0);
    last[i] = 0; cntm[i] = 0; lvlS[i] = 0;
  }
  for (int l = lane; l < A_N + 2; l += 64) cnt[l] = 0;
  __syncthreads();
  for (int s = 0; s < A_N; s++) {
    if (isinS[s]) {             // uniform branch (LDS broadcast)
      int li = 0, m = 0;
      if (lane < 16) { m = membS[s * M_N + lane]; li = last[m]; }
#pragma unroll
      for (int off = 8; off; off >>= 1) li = max(li, __shfl_xor(li, off));
      int L = __shfl(li, 0) + 1;
      if (lane < 16) { last[m] = L; cntm[m]++; }
      if (lane == 0) { lvlS[s] = (short)L; cnt[L]++; }
    }
  }
  if (lane == 0) {
    int acc = 0;
    for (int L = 1; L <= A_N; L++) { cur[L] = acc; acc += cnt[L]; }
    lstart[0] = acc;  // nact
    for (int s = 0; s < A_N; s++) {
      int L = lvlS[s];
      if (L > 0) llist[cur[L]++] = s;
    }
  }
  for (int i = lane; i < A_N; i += 64) fin[i] = cntm[i] & 1;
}

// ---------------- k_scan: single-dispatch DATAFLOW scan (no grid barrier) ----------------
// 16 WGs x 512 threads; WG wg handles llist entries (wg>>1)+8k, dir = wg&1.
// Per-row version counters verF/verB (one per dir), all relaxed agent-scope
// (L3-coherent point ops, NO cache maintenance -- R3's acquire-poll poisoned
// L2; relaxed polls don't). Writer protocol: u-loop's final __syncthreads
// drains vmcnt (all h-stores complete) -> relaxed fetch_add of own dir's
// counter. Consumer: poll both counters >= req. Deadlock-free: 16 WGs all
// resident (1 WG/CU via LDS pad), deps always earlier in level-sorted llist.
// Whh column in registers as packed fp16 (64 VGPRs, v_dot2_f32_f16 w/ fp32
// accumulate); VGPR_Count=112 fits the 128 budget (R11-verified).
#define SPAD 16384  // LDS pad (floats): total ~83 KB > 160/2 -> 1 WG/CU
__global__ __launch_bounds__(512)
void k_scan(
    float* __restrict__ thA, float* __restrict__ thB,
    const int* __restrict__ lstart, const int* __restrict__ llist,
    const int* __restrict__ memb, const int* __restrict__ req,
    int* __restrict__ verF, int* __restrict__ verB,
    const float* __restrict__ Wih4f, const float* __restrict__ Wih4r,
    const unsigned int* __restrict__ whhpf, const unsigned int* __restrict__ whhpr,
    const float* __restrict__ bsumf, const float* __restrict__ bsumr) {
  __shared__ float S[16 * TD_N + SPAD];  // 16 KB used + 64 KB occupancy pad
  __shared__ float garr[4 * H_N];        // gates i,f,g,o 2 KB
  __shared__ unsigned int hp[2 * 64];    // packed fp16 h, ping-pong, 512 B
  __shared__ int memb_s[16];
  __shared__ int par_s[16];
  int tid = threadIdx.x;
  int wg = blockIdx.x;
  int dir = wg & 1;
  int pair = wg >> 1;
  int dmask = dir ? 15 : 0;
  const float4* Wih4 = (const float4*)(dir ? Wih4r : Wih4f);
  const unsigned int* whhp = dir ? whhpr : whhpf;
  float blo = (dir ? bsumr : bsumf)[tid];
  int istanh = ((tid >> 7) == 2);  // gate order i,f,g,o; g-chunk uses tanh
  int* vown = dir ? verB : verF;
  // Whh column in registers, packed fp16: 64 VGPRs, asm-pinned against remat
  unsigned int wreg[64];
#pragma unroll
  for (int k2 = 0; k2 < 64; k2++) wreg[k2] = whhp[k2 * 512 + tid];
#pragma unroll
  for (int k2 = 0; k2 < 64; k2++) asm volatile("" : "+v"(wreg[k2]));

  int nact = lstart[0];
  for (int idx = pair; idx < nact; idx += NWGC / 2) {
    int s = llist[idx];
    if (tid < 16) {
      int m = memb[s * M_N + tid] & (A_N - 1);
      int rq = req[s * M_N + tid];
      memb_s[tid] = m;
      par_s[tid] = rq & 1;
      // wait for both dirs of all prior writers of this row (relaxed L3 polls)
      int tries = 0;
      while (__hip_atomic_load(&verF[m], __ATOMIC_RELAXED, __HIP_MEMORY_SCOPE_AGENT) < rq ||
             __hip_atomic_load(&verB[m], __ATOMIC_RELAXED, __HIP_MEMORY_SCOPE_AGENT) < rq) {
        __builtin_amdgcn_s_sleep(2);
        if (++tries > (1 << 20)) break;  // failsafe: wrong-answer beats hang
      }
    }
    __syncthreads();
    {  // gather 16 member rows (coherent L3 loads); conflict-free q*32+p layout
      int r = tid >> 5, p = tid & 31;
      const float* src = (par_s[r] ? thB : thA) + (size_t)memb_s[r] * TD_N;
      float* dst = S + r * TD_N;
#pragma unroll
      for (int q = 0; q < 8; q++)
        dst[q * 32 + p] = __hip_atomic_load(src + q * 32 + p, __ATOMIC_RELAXED, __HIP_MEMORY_SCOPE_AGENT);
    }
    __syncthreads();
    // ---- input transform (fp32): xa[t] = bsum + seq[t] . Wih[:,tid]
    float xa[16];
#pragma unroll
    for (int t = 0; t < 16; t++) xa[t] = blo;
    {
      const float4* S4 = (const float4*)S;
#pragma unroll 2
      for (int k4 = 0; k4 < 64; k4++) {
        float4 wv = Wih4[k4 * 512 + tid];
#pragma unroll
        for (int t = 0; t < 16; t++) {
          float4 sv = S4[(t ^ dmask) * 64 + k4];
          xa[t] += dot4(sv, wv);
        }
      }
    }
    if (tid < 64) hp[tid] = 0u;  // h0 = 0 (packed), buf 0
    float cst = 0.0f;
    __syncthreads();
    // ---- recurrence, fully unrolled; weights from pinned fp16 registers
#pragma unroll
    for (int u = 0; u < 16; u++) {
      const uint4* hp4 = (const uint4*)(hp + (u & 1) * 64);
      float z0 = 0, z1 = 0, z2 = 0, z3 = 0;
#pragma unroll
      for (int j = 0; j < 16; j++) {
        uint4 hw = hp4[j];  // broadcast read (all lanes same addr)
        z0 = __builtin_amdgcn_fdot2(u2h(wreg[4 * j + 0]), u2h(hw.x), z0, false);
        z1 = __builtin_amdgcn_fdot2(u2h(wreg[4 * j + 1]), u2h(hw.y), z1, false);
        z2 = __builtin_amdgcn_fdot2(u2h(wreg[4 * j + 2]), u2h(hw.z), z2, false);
        z3 = __builtin_amdgcn_fdot2(u2h(wreg[4 * j + 3]), u2h(hw.w), z3, false);
      }
      float z = xa[u] + (z0 + z1) + (z2 + z3);
      garr[tid] = istanh ? tanhf(z) : sigf(z);
      __syncthreads();
      if (tid < H_N) {
        cst = garr[H_N + tid] * cst + garr[tid] * garr[2 * H_N + tid];
        float hv = garr[3 * H_N + tid] * tanhf(cst);
        // pack pair (2t, 2t+1) -> hp word t via shfl (pairs are wave-local)
        float hvn = __shfl_down(hv, 1);
        if (!(tid & 1)) hp[((u + 1) & 1) * 64 + (tid >> 1)] = packh(hv, hvn);
        int r2 = u ^ dmask;                 // fwd: u; bwd: 15-u (rev-aligned)
        float* dst = par_s[r2] ? thA : thB; // write opposite parity buffer
        __hip_atomic_store(dst + (size_t)memb_s[r2] * TD_N + dir * H_N + tid, hv,
                           __ATOMIC_RELAXED, __HIP_MEMORY_SCOPE_AGENT);
      }
      __syncthreads();  // also drains vmcnt: after u=15 all h-stores are complete
    }
    // publish: bump own dir's version for each member row (relaxed; L3-visible)
    if (tid < 16)
      __hip_atomic_fetch_add(&vown[memb_s[tid]], 1, __ATOMIC_RELAXED, __HIP_MEMORY_SCOPE_AGENT);
    __syncthreads();
  }
}

// ---------------- k_actor2: acts = tanh(LN(LN(relu(th)@W3+b3)@W4+b4)) ----------------
__global__ __launch_bounds__(256) void k_actor2(const float* __restrict__ thA, const float* __restrict__ thB,
    const int* __restrict__ fin,
    const float* __restrict__ W3, const float* __restrict__ b3,
    const float* __restrict__ g3, const float* __restrict__ bt3,
    const float* __restrict__ W4, const float* __restrict__ b4,
    const float* __restrict__ g4, const float* __restrict__ bt4,
    float* __restrict__ out) {
  __shared__ float Hs[4 * TD_N];
  __shared__ float H3[4 * TD_N];
  __shared__ float red[4][4][2];
  int tid = threadIdx.x;
  int r0 = blockIdx.x * 4;
  int j = tid;
  for (int i = tid; i < 4 * TD_N; i += 256) {
    int r = i >> 8, col = i & 255;
    int row = r0 + r;
    const float* src = (fin[row] ? thB : thA) + (size_t)row * TD_N + col;
    float v = __hip_atomic_load(src, __ATOMIC_RELAXED, __HIP_MEMORY_SCOPE_AGENT);
    Hs[i] = fmaxf(v, 0.0f);
  }
  __syncthreads();  // all reads of own rows complete before any write below
  float z[4] = {0, 0, 0, 0};
  {
    const float4* S4 = (const float4*)Hs;
    for (int k4 = 0; k4 < 64; k4++) {
      float w0 = W3[(k4 * 4 + 0) * TD_N + j];
      float w1 = W3[(k4 * 4 + 1) * TD_N + j];
      float w2 = W3[(k4 * 4 + 2) * TD_N + j];
      float w3v = W3[(k4 * 4 + 3) * TD_N + j];
#pragma unroll
      for (int r = 0; r < 4; r++) {
        float4 sv = S4[r * 64 + k4];
        z[r] += sv.x * w0 + sv.y * w1 + sv.z * w2 + sv.w * w3v;
      }
    }
  }
  for (int r = 0; r < 4; r++) z[r] += b3[j];
  int w = tid >> 6, lane = tid & 63;
  for (int r = 0; r < 4; r++) {
    float v = z[r], v2 = z[r] * z[r];
    for (int off = 32; off; off >>= 1) { v += __shfl_down(v, off); v2 += __shfl_down(v2, off); }
    if (lane == 0) { red[r][w][0] = v; red[r][w][1] = v2; }
  }
  __syncthreads();
  for (int r = 0; r < 4; r++) {
    float sm = red[r][0][0] + red[r][1][0] + red[r][2][0] + red[r][3][0];
    float sq = red[r][0][1] + red[r][1][1] + red[r][2][1] + red[r][3][1];
    float mean = sm * (1.0f / TD_N);
    float var = sq * (1.0f / TD_N) - mean * mean;
    float rs = 1.0f / sqrtf(var + 1e-5f);
    H3[r * TD_N + j] = (z[r] - mean) * rs * g3[j] + bt3[j];
  }
  __syncthreads();
  float z2a[4] = {0, 0, 0, 0};
  {
    const float4* S4 = (const float4*)H3;
    for (int k4 = 0; k4 < 64; k4++) {
      float w0 = W4[(k4 * 4 + 0) * TD_N + j];
      float w1 = W4[(k4 * 4 + 1) * TD_N + j];
      float w2 = W4[(k4 * 4 + 2) * TD_N + j];
      float w3v = W4[(k4 * 4 + 3) * TD_N + j];
#pragma unroll
      for (int r = 0; r < 4; r++) {
        float4 sv = S4[r * 64 + k4];
        z2a[r] += sv.x * w0 + sv.y * w1 + sv.z * w2 + sv.w * w3v;
      }
    }
  }
  for (int r = 0; r < 4; r++) z2a[r] += b4[j];
  __syncthreads();
  for (int r = 0; r < 4; r++) {
    float v = z2a[r], v2 = z2a[r] * z2a[r];
    for (int off = 32; off; off >>= 1) { v += __shfl_down(v, off); v2 += __shfl_down(v2, off); }
    if (lane == 0) { red[r][w][0] = v; red[r][w][1] = v2; }
  }
  __syncthreads();
  for (int r = 0; r < 4; r++) {
    float sm = red[r][0][0] + red[r][1][0] + red[r][2][0] + red[r][3][0];
    float sq = red[r][0][1] + red[r][1][1] + red[r][2][1] + red[r][3][1];
    float mean = sm * (1.0f / TD_N);
    float var = sq * (1.0f / TD_N) - mean * mean;
    float rs = 1.0f / sqrtf(var + 1e-5f);
    float val = (z2a[r] - mean) * rs * g4[j] + bt4[j];
    out[(size_t)(r0 + r) * TD_N + j] = tanhf(val);
  }
}

extern "C" void kernel_launch(void* const* d_in, const int* in_sizes, int n_in,
                              void* d_out, int out_size, void* d_ws, size_t ws_size,
                              hipStream_t stream) {
  const float* obs = (const float*)d_in[0];
  const unsigned char* C = (const unsigned char*)d_in[1];
  const float* W1 = (const float*)d_in[2];  const float* b1 = (const float*)d_in[3];
  const float* g1 = (const float*)d_in[4];  const float* bt1 = (const float*)d_in[5];
  const float* W2 = (const float*)d_in[6];  const float* b2 = (const float*)d_in[7];
  const float* g2 = (const float*)d_in[8];  const float* bt2 = (const float*)d_in[9];
  const float* aW1 = (const float*)d_in[10]; const float* ab1 = (const float*)d_in[11];
  const float* aW2 = (const float*)d_in[12]; const float* ab2 = (const float*)d_in[13];
  const float* aW3 = (const float*)d_in[14]; const float* ab3 = (const float*)d_in[15];
  const float* Wih_f = (const float*)d_in[16]; const float* Whh_f = (const float*)d_in[17];
  const float* bih_f = (const float*)d_in[18]; const float* bhh_f = (const float*)d_in[19];
  const float* Wih_r = (const float*)d_in[20]; const float* Whh_r = (const float*)d_in[21];
  const float* bih_r = (const float*)d_in[22]; const float* bhh_r = (const float*)d_in[23];
  const float* W3 = (const float*)d_in[24]; const float* b3 = (const float*)d_in[25];
  const float* g3 = (const float*)d_in[26]; const float* bt3 = (const float*)d_in[27];
  const float* W4 = (const float*)d_in[28]; const float* b4 = (const float*)d_in[29];
  const float* g4 = (const float*)d_in[30]; const float* bt4 = (const float*)d_in[31];
  float* out = (float*)d_out;

  // Workspace layout (float offsets). t_buf overlaps thB (dead before k_scan).
  float* ws = (float*)d_ws;
  float* Wih4f = ws;                  // 131072
  float* Wih4r = ws + 131072;         // 131072
  unsigned int* whhpf = (unsigned int*)(ws + 262144);  // 32768 u32
  unsigned int* whhpr = (unsigned int*)(ws + 327680);  // 32768 u32
  float* bsumf = ws + 393216;         // 512
  float* bsumr = ws + 393728;         // 512
  float* thB   = ws + 394240;         // 262144 (parity-1 thoughts buffer)
  float* t_buf = ws + 394240;         // overlap: used only before k_prep/k_scan
  int* ibase   = (int*)(ws + 656384);
  int* membi   = ibase;               // 16384
  int* reqi    = ibase + 16384;       // 16384
  int* isin    = ibase + 32768;       // 1024
  int* flag    = ibase + 33792;       // 64
  int* fin     = ibase + 33856;       // 1024
  int* lstart  = ibase + 34880;       // 64 (nact)
  int* llist   = ibase + 34944;       // 1024
  int* verF    = ibase + 35968;       // 1024
  int* verB    = ibase + 36992;       // 1024
  size_t need = (size_t)(656384 + 38016 + 64) * 4;  // ~2.78 MB
  if (ws_size < need) return;  // diagnosable absmax-fail instead of a fault

  (void)in_sizes; (void)n_in; (void)out_size;

  float* thA = out;  // parity-0 thoughts buffer aliases d_out

  k_cdet<<<1, 64, 0, stream>>>(C, flag);
  k_actor1a<<<256, 256, 0, stream>>>(obs, W1, b1, g1, bt1, t_buf);
  k_actor1b<<<256, 256, 0, stream>>>(t_buf, W2, b2, g2, bt2, thA);
  k_att<<<256, 256, 0, stream>>>(thA, aW1, ab1, aW2, ab2, aW3, ab3, isin);
  k_memb<<<1024, 64, 0, stream>>>(C, flag, membi);
  k_req<<<1024, 256, 0, stream>>>(C, flag, membi, isin, reqi);
  k_prep<<<512, 256, 0, stream>>>(Wih_f, Wih_r, Whh_f, Whh_r, bih_f, bhh_f, bih_r, bhh_r,
                                  Wih4f, Wih4r, whhpf, whhpr, bsumf, bsumr, verF, verB);
  k_lvl<<<1, 64, 0, stream>>>(isin, membi, fin, lstart, llist);
  k_scan<<<NWGC, 512, 0, stream>>>(thA, thB, lstart, llist, membi, reqi, verF, verB,
                                   Wih4f, Wih4r, whhpf, whhpr, bsumf, bsumr);
  k_actor2<<<256, 256, 0, stream>>>(thA, thB, fin, W3, b3, g3, bt3, W4, b4, g4, bt4, out);
}

// Round 13
// 4896.203 us; speedup vs baseline: 4.5526x; 2.5785x over previous
//
#include <hip/hip_runtime.h>
#include <cstdint>
#include <cstddef>
#include <math.h>

#define A_N   1024
#define OBS_N 2048
#define TD_N  256
#define H_N   128
#define M_N   16
#define AE_N  64
#define NWGC  32   // k_scan grid: 32 WGs (16 step-pairs), 1 WG/CU (LDS-forced)

typedef _Float16 h2 __attribute__((ext_vector_type(2)));
typedef _Float16 f16x8 __attribute__((ext_vector_type(8)));
typedef float f32x4 __attribute__((ext_vector_type(4)));

__device__ __forceinline__ float sigf(float x) { return 1.0f / (1.0f + expf(-x)); }
__device__ __forceinline__ h2 u2h(unsigned int u) { union { unsigned int x; h2 h; } c; c.x = u; return c.h; }
__device__ __forceinline__ unsigned int packh(float a, float b) {
  union { h2 h; unsigned int u; } c;
  c.h = (h2){(_Float16)a, (_Float16)b};
  return c.u;
}

// C may arrive as uint8 (1B/elem) or int32 (4B/elem). Detect on device.
__device__ __forceinline__ bool c_at(const unsigned char* C, int as_int, size_t idx) {
  return as_int ? (((const int*)C)[idx] != 0) : (C[idx] != 0);
}

__global__ __launch_bounds__(64) void k_cdet(const unsigned char* __restrict__ C, int* __restrict__ flag) {
  int lane = threadIdx.x;
  int cnt = 0;
  for (int i = lane; i < 4096; i += 64) cnt += (C[i] != 0) ? 1 : 0;
  for (int off = 32; off; off >>= 1) cnt += __shfl_down(cnt, off);
  if (lane == 0) flag[0] = (cnt < 40) ? 1 : 0;
}

// ---------------- k1: t = relu(LN(obs@W1 + b1)) ----------------
__global__ __launch_bounds__(256) void k_actor1a(const float* __restrict__ obs,
    const float* __restrict__ W1, const float* __restrict__ b1,
    const float* __restrict__ g1, const float* __restrict__ bt1,
    float* __restrict__ tout) {
  __shared__ float S[4 * OBS_N];
  __shared__ float red[4][4][2];
  int tid = threadIdx.x;
  int r0 = blockIdx.x * 4;
  {
    const float4* src = (const float4*)(obs + (size_t)r0 * OBS_N);
    float4* dst = (float4*)S;
    for (int i = tid; i < 4 * OBS_N / 4; i += 256) dst[i] = src[i];
  }
  __syncthreads();
  int j = tid;
  float acc0 = 0, acc1 = 0, acc2 = 0, acc3 = 0;
  const float4* S4 = (const float4*)S;
  for (int k4 = 0; k4 < OBS_N / 4; k4++) {
    float w0 = W1[(k4 * 4 + 0) * TD_N + j];
    float w1 = W1[(k4 * 4 + 1) * TD_N + j];
    float w2 = W1[(k4 * 4 + 2) * TD_N + j];
    float w3 = W1[(k4 * 4 + 3) * TD_N + j];
    float4 s0 = S4[0 * 512 + k4], s1 = S4[1 * 512 + k4], s2 = S4[2 * 512 + k4], s3 = S4[3 * 512 + k4];
    acc0 += s0.x * w0 + s0.y * w1 + s0.z * w2 + s0.w * w3;
    acc1 += s1.x * w0 + s1.y * w1 + s1.z * w2 + s1.w * w3;
    acc2 += s2.x * w0 + s2.y * w1 + s2.z * w2 + s2.w * w3;
    acc3 += s3.x * w0 + s3.y * w1 + s3.z * w2 + s3.w * w3;
  }
  float z[4] = {acc0 + b1[j], acc1 + b1[j], acc2 + b1[j], acc3 + b1[j]};
  int w = tid >> 6, lane = tid & 63;
  for (int r = 0; r < 4; r++) {
    float v = z[r], v2 = z[r] * z[r];
    for (int off = 32; off; off >>= 1) { v += __shfl_down(v, off); v2 += __shfl_down(v2, off); }
    if (lane == 0) { red[r][w][0] = v; red[r][w][1] = v2; }
  }
  __syncthreads();
  for (int r = 0; r < 4; r++) {
    float sm = red[r][0][0] + red[r][1][0] + red[r][2][0] + red[r][3][0];
    float sq = red[r][0][1] + red[r][1][1] + red[r][2][1] + red[r][3][1];
    float mean = sm * (1.0f / TD_N);
    float var = sq * (1.0f / TD_N) - mean * mean;
    float rs = 1.0f / sqrtf(var + 1e-5f);
    float val = (z[r] - mean) * rs * g1[j] + bt1[j];
    tout[(size_t)(r0 + r) * TD_N + j] = fmaxf(val, 0.0f);
  }
}

// ---------------- k2: thoughts = LN(t@W2 + b2) -> thA (= d_out) ----------------
__global__ __launch_bounds__(256) void k_actor1b(const float* __restrict__ tin,
    const float* __restrict__ W2, const float* __restrict__ b2,
    const float* __restrict__ g2, const float* __restrict__ bt2,
    float* __restrict__ th) {
  __shared__ float S[4 * TD_N];
  __shared__ float red[4][4][2];
  int tid = threadIdx.x;
  int r0 = blockIdx.x * 4;
  for (int i = tid; i < 4 * TD_N; i += 256) S[i] = tin[(size_t)r0 * TD_N + i];
  __syncthreads();
  int j = tid;
  float z[4] = {0, 0, 0, 0};
  const float4* S4 = (const float4*)S;
  for (int k4 = 0; k4 < TD_N / 4; k4++) {
    float w0 = W2[(k4 * 4 + 0) * TD_N + j];
    float w1 = W2[(k4 * 4 + 1) * TD_N + j];
    float w2v = W2[(k4 * 4 + 2) * TD_N + j];
    float w3 = W2[(k4 * 4 + 3) * TD_N + j];
#pragma unroll
    for (int r = 0; r < 4; r++) {
      float4 sv = S4[r * 64 + k4];
      z[r] += sv.x * w0 + sv.y * w1 + sv.z * w2v + sv.w * w3;
    }
  }
  for (int r = 0; r < 4; r++) z[r] += b2[j];
  int w = tid >> 6, lane = tid & 63;
  for (int r = 0; r < 4; r++) {
    float v = z[r], v2 = z[r] * z[r];
    for (int off = 32; off; off >>= 1) { v += __shfl_down(v, off); v2 += __shfl_down(v2, off); }
    if (lane == 0) { red[r][w][0] = v; red[r][w][1] = v2; }
  }
  __syncthreads();
  for (int r = 0; r < 4; r++) {
    float sm = red[r][0][0] + red[r][1][0] + red[r][2][0] + red[r][3][0];
    float sq = red[r][0][1] + red[r][1][1] + red[r][2][1] + red[r][3][1];
    float mean = sm * (1.0f / TD_N);
    float var = sq * (1.0f / TD_N) - mean * mean;
    float rs = 1.0f / sqrtf(var + 1e-5f);
    th[(size_t)(r0 + r) * TD_N + j] = (z[r] - mean) * rs * g2[j] + bt2[j];
  }
}

// ---------------- k3: attention unit -> is_init (fp64: x>0 decision is razor-thin) ----------------
__global__ __launch_bounds__(256) void k_att(const float* __restrict__ th,
    const float* __restrict__ aW1, const float* __restrict__ ab1,
    const float* __restrict__ aW2, const float* __restrict__ ab2,
    const float* __restrict__ aW3, const float* __restrict__ ab3,
    int* __restrict__ isin) {
  __shared__ float S[4 * TD_N];
  __shared__ double A1[4 * AE_N];
  __shared__ double A2[4 * AE_N];
  int tid = threadIdx.x;
  int r0 = blockIdx.x * 4;
  for (int i = tid; i < 4 * TD_N; i += 256) S[i] = th[(size_t)r0 * TD_N + i];
  __syncthreads();
  int r = tid >> 6, c = tid & 63;
  double acc = 0;
  for (int k = 0; k < TD_N; k++) acc += (double)S[r * TD_N + k] * (double)aW1[k * AE_N + c];
  acc += (double)ab1[c];
  A1[r * AE_N + c] = acc > 0.0 ? acc : 0.0;
  __syncthreads();
  acc = 0;
  for (int k = 0; k < AE_N; k++) acc += A1[r * AE_N + k] * (double)aW2[k * AE_N + c];
  acc += (double)ab2[c];
  A2[r * AE_N + c] = acc > 0.0 ? acc : 0.0;
  __syncthreads();
  double p = A2[r * AE_N + c] * (double)aW3[c];
  for (int off = 32; off; off >>= 1) p += __shfl_down(p, off);
  if (c == 0) isin[r0 + r] = ((p + (double)ab3[0]) > 0.0) ? 1 : 0;
}

// ---------------- k_memb: member indices (ascending) per row ----------------
__global__ __launch_bounds__(64) void k_memb(const unsigned char* __restrict__ C,
    const int* __restrict__ flag, int* __restrict__ memb) {
  int s = blockIdx.x, lane = threadIdx.x;
  int as_int = flag[0];
  if (lane < M_N) memb[s * M_N + lane] = lane;  // safe defaults (never poison)
  __syncthreads();
  int base = 0;
  for (int ch = 0; ch < 16; ch++) {
    int col = ch * 64 + lane;
    bool v = c_at(C, as_int, (size_t)s * A_N + col);
    unsigned long long m = __ballot(v);
    if (v) {
      int pos = base + __popcll(m & ((1ull << lane) - 1ull));
      if (pos < M_N) memb[s * M_N + pos] = col;
    }
    base += __popcll(m);
  }
}

// ---------------- k_req: write ordinal per (step, member slot) ----------------
__global__ __launch_bounds__(256) void k_req(const unsigned char* __restrict__ C,
    const int* __restrict__ flag, const int* __restrict__ memb,
    const int* __restrict__ isin, int* __restrict__ req) {
  __shared__ int Ls[A_N];
  int s = blockIdx.x, tid = threadIdx.x;
  int as_int = flag[0];
  for (int i = tid; i < A_N; i += 256) Ls[i] = isin[i];
  __syncthreads();
  int i = tid >> 4, sub = tid & 15;
  int m = memb[s * M_N + i] & (A_N - 1);
  int cnt = 0;
  for (int s2 = sub; s2 < s; s2 += 16)
    if (Ls[s2] && c_at(C, as_int, (size_t)s2 * A_N + m)) cnt++;
  for (int off = 1; off < 16; off <<= 1) cnt += __shfl_xor(cnt, off);
  if (sub == 0) req[s * M_N + i] = cnt;
}

// ---------------- k_prep: weight re-layouts, bias sums, version-counter reset ----------------
// Wfrag (fp16, MFMA B-fragment order for 16x16x32_f16):
//   uint idx = ((c*32 + tile)*64 + lane)*4 + j, j=0..3 (pairs of halves)
//   gate = tile*16 + (lane&15); k = c*32 + (lane>>4)*8 + 2j
//   value = packh(Wih[gate][k], Wih[gate][k+1])
// Whh packed fp16 pairs: whhp[k2*512+g] = half2(Whh[g][2k2], Whh[g][2k2+1])
__global__ __launch_bounds__(256) void k_prep(
    const float* __restrict__ Wih_f, const float* __restrict__ Wih_r,
    const float* __restrict__ Whh_f, const float* __restrict__ Whh_r,
    const float* __restrict__ bih_f, const float* __restrict__ bhh_f,
    const float* __restrict__ bih_r, const float* __restrict__ bhh_r,
    unsigned int* __restrict__ wfragf, unsigned int* __restrict__ wfragr,
    unsigned int* __restrict__ whhpf, unsigned int* __restrict__ whhpr,
    float* __restrict__ bsumf, float* __restrict__ bsumr,
    int* __restrict__ verF, int* __restrict__ verB) {
  int id = blockIdx.x * 256 + threadIdx.x;  // 512*256 = 131072
  if (id < 65536) {
    int j = id & 3, l = (id >> 2) & 63, tile = (id >> 8) & 31, c = id >> 13;
    int gate = tile * 16 + (l & 15);
    int k = c * 32 + ((l >> 4) << 3) + (j << 1);
    wfragf[id] = packh(Wih_f[gate * TD_N + k], Wih_f[gate * TD_N + k + 1]);
    wfragr[id] = packh(Wih_r[gate * TD_N + k], Wih_r[gate * TD_N + k + 1]);
  }
  if (id < 32768) {
    int g = id & 511, k2 = id >> 9;
    whhpf[id] = packh(Whh_f[g * H_N + 2 * k2], Whh_f[g * H_N + 2 * k2 + 1]);
    whhpr[id] = packh(Whh_r[g * H_N + 2 * k2], Whh_r[g * H_N + 2 * k2 + 1]);
  }
  if (id < 512) { bsumf[id] = bih_f[id] + bhh_f[id]; bsumr[id] = bih_r[id] + bhh_r[id]; }
  if (id < A_N) { verF[id] = 0; verB[id] = 0; }
}

// ---------------- k_lvl: level-sorted active-step list (single wave, LDS-resident) ----------------
__global__ __launch_bounds__(64) void k_lvl(const int* __restrict__ isin,
    const int* __restrict__ memb, int* __restrict__ fin,
    int* __restrict__ lstart, int* __restrict__ llist) {
  __shared__ int membS[A_N * M_N];        // 64 KB
  __shared__ int last[A_N];               // 4 KB
  __shared__ int cnt[A_N + 2];            // 4 KB
  __shared__ int cur[A_N + 2];            // 4 KB
  __shared__ short lvlS[A_N];             // 2 KB
  __shared__ unsigned char isinS[A_N];    // 1 KB
  __shared__ unsigned char cntm[A_N];     // 1 KB
  int lane = threadIdx.x;
  for (int i = lane; i < A_N * M_N; i += 64) membS[i] = memb[i] & (A_N - 1);
  for (int i = lane; i < A_N; i += 64) {
    isinS[i] = (unsigned char)(isin[i] != 0);
    last[i] = 0; cntm[i] = 0; lvlS[i] = 0;
  }
  for (int l = lane; l < A_N + 2; l += 64) cnt[l] = 0;
  __syncthreads();
  for (int s = 0; s < A_N; s++) {
    if (isinS[s]) {             // uniform branch (LDS broadcast)
      int li = 0, m = 0;
      if (lane < 16) { m = membS[s * M_N + lane]; li = last[m]; }
#pragma unroll
      for (int off = 8; off; off >>= 1) li = max(li, __shfl_xor(li, off));
      int L = __shfl(li, 0) + 1;
      if (lane < 16) { last[m] = L; cntm[m]++; }
      if (lane == 0) { lvlS[s] = (short)L; cnt[L]++; }
    }
  }
  if (lane == 0) {
    int acc = 0;
    for (int L = 1; L <= A_N; L++) { cur[L] = acc; acc += cnt[L]; }
    lstart[0] = acc;  // nact
    for (int s = 0; s < A_N; s++) {
      int L = lvlS[s];
      if (L > 0) llist[cur[L]++] = s;
    }
  }
  for (int i = lane; i < A_N; i += 64) fin[i] = cntm[i] & 1;
}

// ---------------- k_scan: single-dispatch DATAFLOW scan, MFMA transform ----------------
// 32 WGs x 512 threads; WG wg handles llist entries (wg>>1)+16k, dir = wg&1.
// Transform: X[16t x 512g] = S.Wih via v_mfma_f32_16x16x32_f16 (fp16 mul, FP32
// accumulate): 32 MFMA/wave replace the 8192 LDS broadcast reads that made
// R6-R12's step ~30us (LDS-issue-bound). B (Wih) pre-packed in exact fragment
// order (coalesced L2 stream, 256 KB/step-dir); A-frags from fp16 S in LDS
// (row stride 528 B breaks the 16-way conflict). Fragment layout (cdna4):
//   A: m=lane&15, k=(lane>>4)*8+i ; B: n=lane&15, k=(lane>>4)*8+i
//   C: col=lane&15, row=(lane>>4)*4+reg  [m89-verified]
// Recurrence: R12's fdot2 path (Whh fp16 in 64 pinned VGPRs); h history to
// LDS, ONE bulk global store after the u-loop (kills 16 per-u vmcnt drains).
// Dependency protocol: R12's relaxed agent-scope version counters (verF/verB).
#define RSH 264   // Sh row stride in halves (528 B = 33*16)
__global__ __launch_bounds__(512)
void k_scan(
    float* __restrict__ thA, float* __restrict__ thB,
    const int* __restrict__ lstart, const int* __restrict__ llist,
    const int* __restrict__ memb, const int* __restrict__ req,
    int* __restrict__ verF, int* __restrict__ verB,
    const unsigned int* __restrict__ wfragf, const unsigned int* __restrict__ wfragr,
    const unsigned int* __restrict__ whhpf, const unsigned int* __restrict__ whhpr,
    const float* __restrict__ bsumf, const float* __restrict__ bsumr) {
  __shared__ __align__(16) unsigned short Sh[16 * RSH];  // 8448 B (fp16 S)
  __shared__ float xa_lds[16 * 512 + 7936];              // 32 KB used + 31 KB pad (1 WG/CU)
  __shared__ float hh[16 * H_N];                         // 8 KB h history
  __shared__ float garr[4 * H_N];                        // 2 KB gates
  __shared__ unsigned int hp[2 * 64];                    // packed fp16 h ping-pong
  __shared__ int memb_s[16];
  __shared__ int par_s[16];
  int tid = threadIdx.x;
  int wg = blockIdx.x;
  int dir = wg & 1;
  int pair = wg >> 1;
  int dmask = dir ? 15 : 0;
  const unsigned int* wfrag = dir ? wfragr : wfragf;
  const unsigned int* whhp = dir ? whhpr : whhpf;
  float blo = (dir ? bsumr : bsumf)[tid];
  int istanh = ((tid >> 7) == 2);  // gate order i,f,g,o; g-chunk uses tanh
  int* vown = dir ? verB : verF;
  int wv = tid >> 6, lane = tid & 63;
  int fm = lane & 15, fkg = lane >> 4;
  // Whh column in registers, packed fp16: 64 VGPRs, asm-pinned against remat
  unsigned int wreg[64];
#pragma unroll
  for (int k2 = 0; k2 < 64; k2++) wreg[k2] = whhp[k2 * 512 + tid];
#pragma unroll
  for (int k2 = 0; k2 < 64; k2++) asm volatile("" : "+v"(wreg[k2]));

  int nact = lstart[0];
  for (int idx = pair; idx < nact; idx += NWGC / 2) {
    int s = llist[idx];
    if (tid < 16) {
      int m = memb[s * M_N + tid] & (A_N - 1);
      int rq = req[s * M_N + tid];
      memb_s[tid] = m;
      par_s[tid] = rq & 1;
      int tries = 0;
      while (__hip_atomic_load(&verF[m], __ATOMIC_RELAXED, __HIP_MEMORY_SCOPE_AGENT) < rq ||
             __hip_atomic_load(&verB[m], __ATOMIC_RELAXED, __HIP_MEMORY_SCOPE_AGENT) < rq) {
        __builtin_amdgcn_s_sleep(2);
        if (++tries > (1 << 20)) break;  // failsafe: wrong-answer beats hang
      }
    }
    __syncthreads();
    {  // gather 16 member rows -> packed fp16 Sh (dir=1 stores reversed order)
      int r = tid >> 5, p = tid & 31;
      int j = r ^ dmask;
      const float* src = (par_s[j] ? thB : thA) + (size_t)memb_s[j] * TD_N + p * 8;
      float v[8];
#pragma unroll
      for (int q = 0; q < 8; q++)
        v[q] = __hip_atomic_load(src + q, __ATOMIC_RELAXED, __HIP_MEMORY_SCOPE_AGENT);
      uint4 pk;
      pk.x = packh(v[0], v[1]); pk.y = packh(v[2], v[3]);
      pk.z = packh(v[4], v[5]); pk.w = packh(v[6], v[7]);
      *(uint4*)((char*)Sh + r * 528 + p * 16) = pk;
    }
    __syncthreads();
    // ---- MFMA transform: xa[t][g] = S . Wih  (bias added later)
    {
#pragma unroll
      for (int t4 = 0; t4 < 4; t4++) {
        int tile = wv * 4 + t4;
        f32x4 acc = {0.0f, 0.0f, 0.0f, 0.0f};
#pragma unroll 2
        for (int c = 0; c < 8; c++) {
          f16x8 af = *(const f16x8*)((const char*)Sh + fm * 528 + c * 64 + fkg * 16);
          union { uint4 u; f16x8 h; } bu;
          bu.u = *(const uint4*)(wfrag + ((size_t)(c * 32 + tile) * 64 + lane) * 4);
          acc = __builtin_amdgcn_mfma_f32_16x16x32_f16(af, bu.h, acc, 0, 0, 0);
        }
#pragma unroll
        for (int r = 0; r < 4; r++)
          xa_lds[(fkg * 4 + r) * 512 + tile * 16 + fm] = acc[r];
      }
    }
    if (tid < 64) hp[tid] = 0u;  // h0 = 0 (packed), buf 0
    float cst = 0.0f;
    __syncthreads();
    // ---- recurrence, fully unrolled; weights from pinned fp16 registers
#pragma unroll
    for (int u = 0; u < 16; u++) {
      float xau = xa_lds[u * 512 + tid] + blo;
      const uint4* hp4 = (const uint4*)(hp + (u & 1) * 64);
      float z0 = 0, z1 = 0, z2 = 0, z3 = 0;
#pragma unroll
      for (int j = 0; j < 16; j++) {
        uint4 hw = hp4[j];  // broadcast read (all lanes same addr)
        z0 = __builtin_amdgcn_fdot2(u2h(wreg[4 * j + 0]), u2h(hw.x), z0, false);
        z1 = __builtin_amdgcn_fdot2(u2h(wreg[4 * j + 1]), u2h(hw.y), z1, false);
        z2 = __builtin_amdgcn_fdot2(u2h(wreg[4 * j + 2]), u2h(hw.z), z2, false);
        z3 = __builtin_amdgcn_fdot2(u2h(wreg[4 * j + 3]), u2h(hw.w), z3, false);
      }
      float z = xau + (z0 + z1) + (z2 + z3);
      garr[tid] = istanh ? tanhf(z) : sigf(z);
      __syncthreads();
      if (tid < H_N) {
        cst = garr[H_N + tid] * cst + garr[tid] * garr[2 * H_N + tid];
        float hv = garr[3 * H_N + tid] * tanhf(cst);
        float hvn = __shfl_down(hv, 1);
        if (!(tid & 1)) hp[((u + 1) & 1) * 64 + (tid >> 1)] = packh(hv, hvn);
        hh[u * H_N + tid] = hv;  // LDS history (bulk-stored after loop)
      }
      __syncthreads();
    }
    // ---- bulk h store: 2048 values, 4 per thread, coalesced per u-row
#pragma unroll
    for (int q = 0; q < 4; q++) {
      int i2 = q * 512 + tid;
      int u = i2 >> 7, col = i2 & 127;
      int slot = u ^ dmask;
      float* dst = (par_s[slot] ? thA : thB) + (size_t)memb_s[slot] * TD_N + dir * H_N + col;
      __hip_atomic_store(dst, hh[u * H_N + col], __ATOMIC_RELAXED, __HIP_MEMORY_SCOPE_AGENT);
    }
    __syncthreads();  // drains vmcnt: all h-stores L3-resident before publish
    if (tid < 16)
      __hip_atomic_fetch_add(&vown[memb_s[tid]], 1, __ATOMIC_RELAXED, __HIP_MEMORY_SCOPE_AGENT);
    __syncthreads();
  }
}

// ---------------- k_actor2: acts = tanh(LN(LN(relu(th)@W3+b3)@W4+b4)) ----------------
__global__ __launch_bounds__(256) void k_actor2(const float* __restrict__ thA, const float* __restrict__ thB,
    const int* __restrict__ fin,
    const float* __restrict__ W3, const float* __restrict__ b3,
    const float* __restrict__ g3, const float* __restrict__ bt3,
    const float* __restrict__ W4, const float* __restrict__ b4,
    const float* __restrict__ g4, const float* __restrict__ bt4,
    float* __restrict__ out) {
  __shared__ float Hs[4 * TD_N];
  __shared__ float H3[4 * TD_N];
  __shared__ float red[4][4][2];
  int tid = threadIdx.x;
  int r0 = blockIdx.x * 4;
  int j = tid;
  for (int i = tid; i < 4 * TD_N; i += 256) {
    int r = i >> 8, col = i & 255;
    int row = r0 + r;
    const float* src = (fin[row] ? thB : thA) + (size_t)row * TD_N + col;
    float v = __hip_atomic_load(src, __ATOMIC_RELAXED, __HIP_MEMORY_SCOPE_AGENT);
    Hs[i] = fmaxf(v, 0.0f);
  }
  __syncthreads();  // all reads of own rows complete before any write below
  float z[4] = {0, 0, 0, 0};
  {
    const float4* S4 = (const float4*)Hs;
    for (int k4 = 0; k4 < 64; k4++) {
      float w0 = W3[(k4 * 4 + 0) * TD_N + j];
      float w1 = W3[(k4 * 4 + 1) * TD_N + j];
      float w2 = W3[(k4 * 4 + 2) * TD_N + j];
      float w3v = W3[(k4 * 4 + 3) * TD_N + j];
#pragma unroll
      for (int r = 0; r < 4; r++) {
        float4 sv = S4[r * 64 + k4];
        z[r] += sv.x * w0 + sv.y * w1 + sv.z * w2 + sv.w * w3v;
      }
    }
  }
  for (int r = 0; r < 4; r++) z[r] += b3[j];
  int w = tid >> 6, lane = tid & 63;
  for (int r = 0; r < 4; r++) {
    float v = z[r], v2 = z[r] * z[r];
    for (int off = 32; off; off >>= 1) { v += __shfl_down(v, off); v2 += __shfl_down(v2, off); }
    if (lane == 0) { red[r][w][0] = v; red[r][w][1] = v2; }
  }
  __syncthreads();
  for (int r = 0; r < 4; r++) {
    float sm = red[r][0][0] + red[r][1][0] + red[r][2][0] + red[r][3][0];
    float sq = red[r][0][1] + red[r][1][1] + red[r][2][1] + red[r][3][1];
    float mean = sm * (1.0f / TD_N);
    float var = sq * (1.0f / TD_N) - mean * mean;
    float rs = 1.0f / sqrtf(var + 1e-5f);
    H3[r * TD_N + j] = (z[r] - mean) * rs * g3[j] + bt3[j];
  }
  __syncthreads();
  float z2a[4] = {0, 0, 0, 0};
  {
    const float4* S4 = (const float4*)H3;
    for (int k4 = 0; k4 < 64; k4++) {
      float w0 = W4[(k4 * 4 + 0) * TD_N + j];
      float w1 = W4[(k4 * 4 + 1) * TD_N + j];
      float w2 = W4[(k4 * 4 + 2) * TD_N + j];
      float w3v = W4[(k4 * 4 + 3) * TD_N + j];
#pragma unroll
      for (int r = 0; r < 4; r++) {
        float4 sv = S4[r * 64 + k4];
        z2a[r] += sv.x * w0 + sv.y * w1 + sv.z * w2 + sv.w * w3v;
      }
    }
  }
  for (int r = 0; r < 4; r++) z2a[r] += b4[j];
  __syncthreads();
  for (int r = 0; r < 4; r++) {
    float v = z2a[r], v2 = z2a[r] * z2a[r];
    for (int off = 32; off; off >>= 1) { v += __shfl_down(v, off); v2 += __shfl_down(v2, off); }
    if (lane == 0) { red[r][w][0] = v; red[r][w][1] = v2; }
  }
  __syncthreads();
  for (int r = 0; r < 4; r++) {
    float sm = red[r][0][0] + red[r][1][0] + red[r][2][0] + red[r][3][0];
    float sq = red[r][0][1] + red[r][1][1] + red[r][2][1] + red[r][3][1];
    float mean = sm * (1.0f / TD_N);
    float var = sq * (1.0f / TD_N) - mean * mean;
    float rs = 1.0f / sqrtf(var + 1e-5f);
    float val = (z2a[r] - mean) * rs * g4[j] + bt4[j];
    out[(size_t)(r0 + r) * TD_N + j] = tanhf(val);
  }
}

extern "C" void kernel_launch(void* const* d_in, const int* in_sizes, int n_in,
                              void* d_out, int out_size, void* d_ws, size_t ws_size,
                              hipStream_t stream) {
  const float* obs = (const float*)d_in[0];
  const unsigned char* C = (const unsigned char*)d_in[1];
  const float* W1 = (const float*)d_in[2];  const float* b1 = (const float*)d_in[3];
  const float* g1 = (const float*)d_in[4];  const float* bt1 = (const float*)d_in[5];
  const float* W2 = (const float*)d_in[6];  const float* b2 = (const float*)d_in[7];
  const float* g2 = (const float*)d_in[8];  const float* bt2 = (const float*)d_in[9];
  const float* aW1 = (const float*)d_in[10]; const float* ab1 = (const float*)d_in[11];
  const float* aW2 = (const float*)d_in[12]; const float* ab2 = (const float*)d_in[13];
  const float* aW3 = (const float*)d_in[14]; const float* ab3 = (const float*)d_in[15];
  const float* Wih_f = (const float*)d_in[16]; const float* Whh_f = (const float*)d_in[17];
  const float* bih_f = (const float*)d_in[18]; const float* bhh_f = (const float*)d_in[19];
  const float* Wih_r = (const float*)d_in[20]; const float* Whh_r = (const float*)d_in[21];
  const float* bih_r = (const float*)d_in[22]; const float* bhh_r = (const float*)d_in[23];
  const float* W3 = (const float*)d_in[24]; const float* b3 = (const float*)d_in[25];
  const float* g3 = (const float*)d_in[26]; const float* bt3 = (const float*)d_in[27];
  const float* W4 = (const float*)d_in[28]; const float* b4 = (const float*)d_in[29];
  const float* g4 = (const float*)d_in[30]; const float* bt4 = (const float*)d_in[31];
  float* out = (float*)d_out;

  // Workspace layout (float offsets). t_buf overlaps thB (dead before k_scan).
  float* ws = (float*)d_ws;
  unsigned int* wfragf = (unsigned int*)ws;             // 65536 u32 (uses 256 KB of 512 KB slot)
  unsigned int* wfragr = (unsigned int*)(ws + 131072);  // 65536 u32
  unsigned int* whhpf = (unsigned int*)(ws + 262144);   // 32768 u32
  unsigned int* whhpr = (unsigned int*)(ws + 327680);   // 32768 u32
  float* bsumf = ws + 393216;         // 512
  float* bsumr = ws + 393728;         // 512
  float* thB   = ws + 394240;         // 262144 (parity-1 thoughts buffer)
  float* t_buf = ws + 394240;         // overlap: used only before k_prep/k_scan
  int* ibase   = (int*)(ws + 656384);
  int* membi   = ibase;               // 16384
  int* reqi    = ibase + 16384;       // 16384
  int* isin    = ibase + 32768;       // 1024
  int* flag    = ibase + 33792;       // 64
  int* fin     = ibase + 33856;       // 1024
  int* lstart  = ibase + 34880;       // 64 (nact)
  int* llist   = ibase + 34944;       // 1024
  int* verF    = ibase + 35968;       // 1024
  int* verB    = ibase + 36992;       // 1024
  size_t need = (size_t)(656384 + 38016 + 64) * 4;  // ~2.78 MB
  if (ws_size < need) return;  // diagnosable absmax-fail instead of a fault

  (void)in_sizes; (void)n_in; (void)out_size;

  float* thA = out;  // parity-0 thoughts buffer aliases d_out

  k_cdet<<<1, 64, 0, stream>>>(C, flag);
  k_actor1a<<<256, 256, 0, stream>>>(obs, W1, b1, g1, bt1, t_buf);
  k_actor1b<<<256, 256, 0, stream>>>(t_buf, W2, b2, g2, bt2, thA);
  k_att<<<256, 256, 0, stream>>>(thA, aW1, ab1, aW2, ab2, aW3, ab3, isin);
  k_memb<<<1024, 64, 0, stream>>>(C, flag, membi);
  k_req<<<1024, 256, 0, stream>>>(C, flag, membi, isin, reqi);
  k_prep<<<512, 256, 0, stream>>>(Wih_f, Wih_r, Whh_f, Whh_r, bih_f, bhh_f, bih_r, bhh_r,
                                  wfragf, wfragr, whhpf, whhpr, bsumf, bsumr, verF, verB);
  k_lvl<<<1, 64, 0, stream>>>(isin, membi, fin, lstart, llist);
  k_scan<<<NWGC, 512, 0, stream>>>(thA, thB, lstart, llist, membi, reqi, verF, verB,
                                   wfragf, wfragr, whhpf, whhpr, bsumf, bsumr);
  k_actor2<<<256, 256, 0, stream>>>(thA, thB, fin, W3, b3, g3, bt3, W4, b4, g4, bt4, out);
}

// Round 14
// 4648.121 us; speedup vs baseline: 4.7956x; 1.0534x over previous
//
#include <hip/hip_runtime.h>
#include <cstdint>
#include <cstddef>
#include <math.h>

#define A_N   1024
#define OBS_N 2048
#define TD_N  256
#define H_N   128
#define M_N   16
#define AE_N  64
#define NWGC  32   // k_scan grid: 32 WGs (16 step-pairs), 1 WG/CU (LDS-forced)

typedef _Float16 h2 __attribute__((ext_vector_type(2)));
typedef _Float16 f16x8 __attribute__((ext_vector_type(8)));
typedef float f32x4 __attribute__((ext_vector_type(4)));

__device__ __forceinline__ float sigf(float x) { return 1.0f / (1.0f + expf(-x)); }
__device__ __forceinline__ h2 u2h(unsigned int u) { union { unsigned int x; h2 h; } c; c.x = u; return c.h; }
__device__ __forceinline__ unsigned int packh(float a, float b) {
  union { h2 h; unsigned int u; } c;
  c.h = (h2){(_Float16)a, (_Float16)b};
  return c.u;
}

// C may arrive as uint8 (1B/elem) or int32 (4B/elem). Detect on device.
__device__ __forceinline__ bool c_at(const unsigned char* C, int as_int, size_t idx) {
  return as_int ? (((const int*)C)[idx] != 0) : (C[idx] != 0);
}

__global__ __launch_bounds__(64) void k_cdet(const unsigned char* __restrict__ C, int* __restrict__ flag) {
  int lane = threadIdx.x;
  int cnt = 0;
  for (int i = lane; i < 4096; i += 64) cnt += (C[i] != 0) ? 1 : 0;
  for (int off = 32; off; off >>= 1) cnt += __shfl_down(cnt, off);
  if (lane == 0) flag[0] = (cnt < 40) ? 1 : 0;
}

// ---------------- k1: t = relu(LN(obs@W1 + b1)) ----------------
__global__ __launch_bounds__(256) void k_actor1a(const float* __restrict__ obs,
    const float* __restrict__ W1, const float* __restrict__ b1,
    const float* __restrict__ g1, const float* __restrict__ bt1,
    float* __restrict__ tout) {
  __shared__ float S[4 * OBS_N];
  __shared__ float red[4][4][2];
  int tid = threadIdx.x;
  int r0 = blockIdx.x * 4;
  {
    const float4* src = (const float4*)(obs + (size_t)r0 * OBS_N);
    float4* dst = (float4*)S;
    for (int i = tid; i < 4 * OBS_N / 4; i += 256) dst[i] = src[i];
  }
  __syncthreads();
  int j = tid;
  float acc0 = 0, acc1 = 0, acc2 = 0, acc3 = 0;
  const float4* S4 = (const float4*)S;
  for (int k4 = 0; k4 < OBS_N / 4; k4++) {
    float w0 = W1[(k4 * 4 + 0) * TD_N + j];
    float w1 = W1[(k4 * 4 + 1) * TD_N + j];
    float w2 = W1[(k4 * 4 + 2) * TD_N + j];
    float w3 = W1[(k4 * 4 + 3) * TD_N + j];
    float4 s0 = S4[0 * 512 + k4], s1 = S4[1 * 512 + k4], s2 = S4[2 * 512 + k4], s3 = S4[3 * 512 + k4];
    acc0 += s0.x * w0 + s0.y * w1 + s0.z * w2 + s0.w * w3;
    acc1 += s1.x * w0 + s1.y * w1 + s1.z * w2 + s1.w * w3;
    acc2 += s2.x * w0 + s2.y * w1 + s2.z * w2 + s2.w * w3;
    acc3 += s3.x * w0 + s3.y * w1 + s3.z * w2 + s3.w * w3;
  }
  float z[4] = {acc0 + b1[j], acc1 + b1[j], acc2 + b1[j], acc3 + b1[j]};
  int w = tid >> 6, lane = tid & 63;
  for (int r = 0; r < 4; r++) {
    float v = z[r], v2 = z[r] * z[r];
    for (int off = 32; off; off >>= 1) { v += __shfl_down(v, off); v2 += __shfl_down(v2, off); }
    if (lane == 0) { red[r][w][0] = v; red[r][w][1] = v2; }
  }
  __syncthreads();
  for (int r = 0; r < 4; r++) {
    float sm = red[r][0][0] + red[r][1][0] + red[r][2][0] + red[r][3][0];
    float sq = red[r][0][1] + red[r][1][1] + red[r][2][1] + red[r][3][1];
    float mean = sm * (1.0f / TD_N);
    float var = sq * (1.0f / TD_N) - mean * mean;
    float rs = 1.0f / sqrtf(var + 1e-5f);
    float val = (z[r] - mean) * rs * g1[j] + bt1[j];
    tout[(size_t)(r0 + r) * TD_N + j] = fmaxf(val, 0.0f);
  }
}

// ---------------- k2: thoughts = LN(t@W2 + b2) -> thA (= d_out) ----------------
__global__ __launch_bounds__(256) void k_actor1b(const float* __restrict__ tin,
    const float* __restrict__ W2, const float* __restrict__ b2,
    const float* __restrict__ g2, const float* __restrict__ bt2,
    float* __restrict__ th) {
  __shared__ float S[4 * TD_N];
  __shared__ float red[4][4][2];
  int tid = threadIdx.x;
  int r0 = blockIdx.x * 4;
  for (int i = tid; i < 4 * TD_N; i += 256) S[i] = tin[(size_t)r0 * TD_N + i];
  __syncthreads();
  int j = tid;
  float z[4] = {0, 0, 0, 0};
  const float4* S4 = (const float4*)S;
  for (int k4 = 0; k4 < TD_N / 4; k4++) {
    float w0 = W2[(k4 * 4 + 0) * TD_N + j];
    float w1 = W2[(k4 * 4 + 1) * TD_N + j];
    float w2v = W2[(k4 * 4 + 2) * TD_N + j];
    float w3 = W2[(k4 * 4 + 3) * TD_N + j];
#pragma unroll
    for (int r = 0; r < 4; r++) {
      float4 sv = S4[r * 64 + k4];
      z[r] += sv.x * w0 + sv.y * w1 + sv.z * w2v + sv.w * w3;
    }
  }
  for (int r = 0; r < 4; r++) z[r] += b2[j];
  int w = tid >> 6, lane = tid & 63;
  for (int r = 0; r < 4; r++) {
    float v = z[r], v2 = z[r] * z[r];
    for (int off = 32; off; off >>= 1) { v += __shfl_down(v, off); v2 += __shfl_down(v2, off); }
    if (lane == 0) { red[r][w][0] = v; red[r][w][1] = v2; }
  }
  __syncthreads();
  for (int r = 0; r < 4; r++) {
    float sm = red[r][0][0] + red[r][1][0] + red[r][2][0] + red[r][3][0];
    float sq = red[r][0][1] + red[r][1][1] + red[r][2][1] + red[r][3][1];
    float mean = sm * (1.0f / TD_N);
    float var = sq * (1.0f / TD_N) - mean * mean;
    float rs = 1.0f / sqrtf(var + 1e-5f);
    th[(size_t)(r0 + r) * TD_N + j] = (z[r] - mean) * rs * g2[j] + bt2[j];
  }
}

// ---------------- k3: attention unit -> is_init (fp64: x>0 decision is razor-thin) ----------------
__global__ __launch_bounds__(256) void k_att(const float* __restrict__ th,
    const float* __restrict__ aW1, const float* __restrict__ ab1,
    const float* __restrict__ aW2, const float* __restrict__ ab2,
    const float* __restrict__ aW3, const float* __restrict__ ab3,
    int* __restrict__ isin) {
  __shared__ float S[4 * TD_N];
  __shared__ double A1[4 * AE_N];
  __shared__ double A2[4 * AE_N];
  int tid = threadIdx.x;
  int r0 = blockIdx.x * 4;
  for (int i = tid; i < 4 * TD_N; i += 256) S[i] = th[(size_t)r0 * TD_N + i];
  __syncthreads();
  int r = tid >> 6, c = tid & 63;
  double acc = 0;
  for (int k = 0; k < TD_N; k++) acc += (double)S[r * TD_N + k] * (double)aW1[k * AE_N + c];
  acc += (double)ab1[c];
  A1[r * AE_N + c] = acc > 0.0 ? acc : 0.0;
  __syncthreads();
  acc = 0;
  for (int k = 0; k < AE_N; k++) acc += A1[r * AE_N + k] * (double)aW2[k * AE_N + c];
  acc += (double)ab2[c];
  A2[r * AE_N + c] = acc > 0.0 ? acc : 0.0;
  __syncthreads();
  double p = A2[r * AE_N + c] * (double)aW3[c];
  for (int off = 32; off; off >>= 1) p += __shfl_down(p, off);
  if (c == 0) isin[r0 + r] = ((p + (double)ab3[0]) > 0.0) ? 1 : 0;
}

// ---------------- k_memb: member indices (ascending) per row ----------------
__global__ __launch_bounds__(64) void k_memb(const unsigned char* __restrict__ C,
    const int* __restrict__ flag, int* __restrict__ memb) {
  int s = blockIdx.x, lane = threadIdx.x;
  int as_int = flag[0];
  if (lane < M_N) memb[s * M_N + lane] = lane;  // safe defaults (never poison)
  __syncthreads();
  int base = 0;
  for (int ch = 0; ch < 16; ch++) {
    int col = ch * 64 + lane;
    bool v = c_at(C, as_int, (size_t)s * A_N + col);
    unsigned long long m = __ballot(v);
    if (v) {
      int pos = base + __popcll(m & ((1ull << lane) - 1ull));
      if (pos < M_N) memb[s * M_N + pos] = col;
    }
    base += __popcll(m);
  }
}

// ---------------- k_req: write ordinal per (step, member slot) ----------------
__global__ __launch_bounds__(256) void k_req(const unsigned char* __restrict__ C,
    const int* __restrict__ flag, const int* __restrict__ memb,
    const int* __restrict__ isin, int* __restrict__ req) {
  __shared__ int Ls[A_N];
  int s = blockIdx.x, tid = threadIdx.x;
  int as_int = flag[0];
  for (int i = tid; i < A_N; i += 256) Ls[i] = isin[i];
  __syncthreads();
  int i = tid >> 4, sub = tid & 15;
  int m = memb[s * M_N + i] & (A_N - 1);
  int cnt = 0;
  for (int s2 = sub; s2 < s; s2 += 16)
    if (Ls[s2] && c_at(C, as_int, (size_t)s2 * A_N + m)) cnt++;
  for (int off = 1; off < 16; off <<= 1) cnt += __shfl_xor(cnt, off);
  if (sub == 0) req[s * M_N + i] = cnt;
}

// ---------------- k_prep: weight re-layouts, bias sums, version-counter reset ----------------
__global__ __launch_bounds__(256) void k_prep(
    const float* __restrict__ Wih_f, const float* __restrict__ Wih_r,
    const float* __restrict__ Whh_f, const float* __restrict__ Whh_r,
    const float* __restrict__ bih_f, const float* __restrict__ bhh_f,
    const float* __restrict__ bih_r, const float* __restrict__ bhh_r,
    unsigned int* __restrict__ wfragf, unsigned int* __restrict__ wfragr,
    unsigned int* __restrict__ whhpf, unsigned int* __restrict__ whhpr,
    float* __restrict__ bsumf, float* __restrict__ bsumr,
    int* __restrict__ verF, int* __restrict__ verB) {
  int id = blockIdx.x * 256 + threadIdx.x;  // 512*256 = 131072
  if (id < 65536) {
    int j = id & 3, l = (id >> 2) & 63, tile = (id >> 8) & 31, c = id >> 13;
    int gate = tile * 16 + (l & 15);
    int k = c * 32 + ((l >> 4) << 3) + (j << 1);
    wfragf[id] = packh(Wih_f[gate * TD_N + k], Wih_f[gate * TD_N + k + 1]);
    wfragr[id] = packh(Wih_r[gate * TD_N + k], Wih_r[gate * TD_N + k + 1]);
  }
  if (id < 32768) {
    int g = id & 511, k2 = id >> 9;
    whhpf[id] = packh(Whh_f[g * H_N + 2 * k2], Whh_f[g * H_N + 2 * k2 + 1]);
    whhpr[id] = packh(Whh_r[g * H_N + 2 * k2], Whh_r[g * H_N + 2 * k2 + 1]);
  }
  if (id < 512) { bsumf[id] = bih_f[id] + bhh_f[id]; bsumr[id] = bih_r[id] + bhh_r[id]; }
  if (id < A_N) { verF[id] = 0; verB[id] = 0; }
}

// ---------------- k_lvl: level-sorted active-step list (single wave, LDS-resident) ----------------
__global__ __launch_bounds__(64) void k_lvl(const int* __restrict__ isin,
    const int* __restrict__ memb, int* __restrict__ fin,
    int* __restrict__ lstart, int* __restrict__ llist) {
  __shared__ int membS[A_N * M_N];        // 64 KB
  __shared__ int last[A_N];               // 4 KB
  __shared__ int cnt[A_N + 2];            // 4 KB
  __shared__ int cur[A_N + 2];            // 4 KB
  __shared__ short lvlS[A_N];             // 2 KB
  __shared__ unsigned char isinS[A_N];    // 1 KB
  __shared__ unsigned char cntm[A_N];     // 1 KB
  int lane = threadIdx.x;
  for (int i = lane; i < A_N * M_N; i += 64) membS[i] = memb[i] & (A_N - 1);
  for (int i = lane; i < A_N; i += 64) {
    isinS[i] = (unsigned char)(isin[i] != 0);
    last[i] = 0; cntm[i] = 0; lvlS[i] = 0;
  }
  for (int l = lane; l < A_N + 2; l += 64) cnt[l] = 0;
  __syncthreads();
  for (int s = 0; s < A_N; s++) {
    if (isinS[s]) {             // uniform branch (LDS broadcast)
      int li = 0, m = 0;
      if (lane < 16) { m = membS[s * M_N + lane]; li = last[m]; }
#pragma unroll
      for (int off = 8; off; off >>= 1) li = max(li, __shfl_xor(li, off));
      int L = __shfl(li, 0) + 1;
      if (lane < 16) { last[m] = L; cntm[m]++; }
      if (lane == 0) { lvlS[s] = (short)L; cnt[L]++; }
    }
  }
  if (lane == 0) {
    int acc = 0;
    for (int L = 1; L <= A_N; L++) { cur[L] = acc; acc += cnt[L]; }
    lstart[0] = acc;  // nact
    for (int s = 0; s < A_N; s++) {
      int L = lvlS[s];
      if (L > 0) llist[cur[L]++] = s;
    }
  }
  for (int i = lane; i < A_N; i += 64) fin[i] = cntm[i] & 1;
}

// ---------------- k_scan: single-dispatch DATAFLOW scan, MFMA transform ----------------
// R13 structure + EARLY PER-ROW PUBLISH: row r2=u^dmask is final at timestep u;
// the u-loop's trailing __syncthreads drains vmcnt(0), so bumping that row's
// version right after it costs zero extra sync. Consumers' limiting member is
// published ~5/16 of a recurrence earlier -> shorter critical-path hop.
// Transform: v_mfma_f32_16x16x32_f16 (fp32 accumulate), B pre-packed in
// fragment order; A from fp16 S in LDS (528 B row stride).
// Recurrence: Whh fp16 in 64 pinned VGPRs, fdot2 w/ fp32 accumulate, 8 chains.
#define RSH 264   // Sh row stride in halves (528 B = 33*16)
__global__ __launch_bounds__(512)
void k_scan(
    float* __restrict__ thA, float* __restrict__ thB,
    const int* __restrict__ lstart, const int* __restrict__ llist,
    const int* __restrict__ memb, const int* __restrict__ req,
    int* __restrict__ verF, int* __restrict__ verB,
    const unsigned int* __restrict__ wfragf, const unsigned int* __restrict__ wfragr,
    const unsigned int* __restrict__ whhpf, const unsigned int* __restrict__ whhpr,
    const float* __restrict__ bsumf, const float* __restrict__ bsumr) {
  __shared__ __align__(16) unsigned short Sh[16 * RSH];  // 8448 B (fp16 S)
  __shared__ float xa_lds[16 * 512 + 9984];              // 32 KB used + 39 KB pad (1 WG/CU)
  __shared__ float garr[4 * H_N];                        // 2 KB gates
  __shared__ unsigned int hp[2 * 64];                    // packed fp16 h ping-pong
  __shared__ int memb_s[16];
  __shared__ int par_s[16];
  int tid = threadIdx.x;
  int wg = blockIdx.x;
  int dir = wg & 1;
  int pair = wg >> 1;
  int dmask = dir ? 15 : 0;
  const unsigned int* wfrag = dir ? wfragr : wfragf;
  const unsigned int* whhp = dir ? whhpr : whhpf;
  float blo = (dir ? bsumr : bsumf)[tid];
  int istanh = ((tid >> 7) == 2);  // gate order i,f,g,o; g-chunk uses tanh
  int* vown = dir ? verB : verF;
  int wv = tid >> 6, lane = tid & 63;
  int fm = lane & 15, fkg = lane >> 4;
  // Whh column in registers, packed fp16: 64 VGPRs, asm-pinned against remat
  unsigned int wreg[64];
#pragma unroll
  for (int k2 = 0; k2 < 64; k2++) wreg[k2] = whhp[k2 * 512 + tid];
#pragma unroll
  for (int k2 = 0; k2 < 64; k2++) asm volatile("" : "+v"(wreg[k2]));

  int nact = lstart[0];
  for (int idx = pair; idx < nact; idx += NWGC / 2) {
    int s = llist[idx];
    if (tid < 16) {
      int m = memb[s * M_N + tid] & (A_N - 1);
      int rq = req[s * M_N + tid];
      memb_s[tid] = m;
      par_s[tid] = rq & 1;
      int tries = 0;
      while (__hip_atomic_load(&verF[m], __ATOMIC_RELAXED, __HIP_MEMORY_SCOPE_AGENT) < rq ||
             __hip_atomic_load(&verB[m], __ATOMIC_RELAXED, __HIP_MEMORY_SCOPE_AGENT) < rq) {
        __builtin_amdgcn_s_sleep(1);
        if (++tries > (1 << 21)) break;  // failsafe: wrong-answer beats hang
      }
    }
    __syncthreads();
    {  // gather 16 member rows -> packed fp16 Sh (dir=1 stores reversed order)
      int r = tid >> 5, p = tid & 31;
      int j = r ^ dmask;
      const float* src = (par_s[j] ? thB : thA) + (size_t)memb_s[j] * TD_N + p * 8;
      float v[8];
#pragma unroll
      for (int q = 0; q < 8; q++)
        v[q] = __hip_atomic_load(src + q, __ATOMIC_RELAXED, __HIP_MEMORY_SCOPE_AGENT);
      uint4 pk;
      pk.x = packh(v[0], v[1]); pk.y = packh(v[2], v[3]);
      pk.z = packh(v[4], v[5]); pk.w = packh(v[6], v[7]);
      *(uint4*)((char*)Sh + r * 528 + p * 16) = pk;
    }
    __syncthreads();
    // ---- MFMA transform: xa[t][g] = S . Wih  (bias added later)
    {
#pragma unroll
      for (int t4 = 0; t4 < 4; t4++) {
        int tile = wv * 4 + t4;
        f32x4 acc = {0.0f, 0.0f, 0.0f, 0.0f};
#pragma unroll 2
        for (int c = 0; c < 8; c++) {
          f16x8 af = *(const f16x8*)((const char*)Sh + fm * 528 + c * 64 + fkg * 16);
          union { uint4 u; f16x8 h; } bu;
          bu.u = *(const uint4*)(wfrag + ((size_t)(c * 32 + tile) * 64 + lane) * 4);
          acc = __builtin_amdgcn_mfma_f32_16x16x32_f16(af, bu.h, acc, 0, 0, 0);
        }
#pragma unroll
        for (int r = 0; r < 4; r++)
          xa_lds[(fkg * 4 + r) * 512 + tile * 16 + fm] = acc[r];
      }
    }
    if (tid < 64) hp[tid] = 0u;  // h0 = 0 (packed), buf 0
    float cst = 0.0f;
    __syncthreads();
    // ---- recurrence, fully unrolled; per-u row store + EARLY publish
#pragma unroll
    for (int u = 0; u < 16; u++) {
      float xau = xa_lds[u * 512 + tid] + blo;
      const uint4* hp4 = (const uint4*)(hp + (u & 1) * 64);
      float z0 = 0, z1 = 0, z2 = 0, z3 = 0, z4 = 0, z5 = 0, z6 = 0, z7 = 0;
#pragma unroll
      for (int j = 0; j < 16; j += 2) {
        uint4 ha = hp4[j], hb = hp4[j + 1];  // broadcast reads
        z0 = __builtin_amdgcn_fdot2(u2h(wreg[4 * j + 0]), u2h(ha.x), z0, false);
        z1 = __builtin_amdgcn_fdot2(u2h(wreg[4 * j + 1]), u2h(ha.y), z1, false);
        z2 = __builtin_amdgcn_fdot2(u2h(wreg[4 * j + 2]), u2h(ha.z), z2, false);
        z3 = __builtin_amdgcn_fdot2(u2h(wreg[4 * j + 3]), u2h(ha.w), z3, false);
        z4 = __builtin_amdgcn_fdot2(u2h(wreg[4 * j + 4]), u2h(hb.x), z4, false);
        z5 = __builtin_amdgcn_fdot2(u2h(wreg[4 * j + 5]), u2h(hb.y), z5, false);
        z6 = __builtin_amdgcn_fdot2(u2h(wreg[4 * j + 6]), u2h(hb.z), z6, false);
        z7 = __builtin_amdgcn_fdot2(u2h(wreg[4 * j + 7]), u2h(hb.w), z7, false);
      }
      float z = xau + ((z0 + z1) + (z2 + z3)) + ((z4 + z5) + (z6 + z7));
      garr[tid] = istanh ? tanhf(z) : sigf(z);
      __syncthreads();
      int r2 = u ^ dmask;                 // fwd: u; bwd: 15-u (rev-aligned)
      if (tid < H_N) {
        cst = garr[H_N + tid] * cst + garr[tid] * garr[2 * H_N + tid];
        float hv = garr[3 * H_N + tid] * tanhf(cst);
        float hvn = __shfl_down(hv, 1);
        if (!(tid & 1)) hp[((u + 1) & 1) * 64 + (tid >> 1)] = packh(hv, hvn);
        float* dst = par_s[r2] ? thA : thB; // write opposite parity buffer
        __hip_atomic_store(dst + (size_t)memb_s[r2] * TD_N + dir * H_N + tid, hv,
                           __ATOMIC_RELAXED, __HIP_MEMORY_SCOPE_AGENT);
      }
      __syncthreads();  // drains vmcnt: row r2's stores are globally complete
      // EARLY publish: row r2 is final for this dir -> release it now
      if (tid == 0)
        __hip_atomic_fetch_add(&vown[memb_s[r2]], 1, __ATOMIC_RELAXED, __HIP_MEMORY_SCOPE_AGENT);
    }
  }
}

// ---------------- k_actor2: acts = tanh(LN(LN(relu(th)@W3+b3)@W4+b4)) ----------------
__global__ __launch_bounds__(256) void k_actor2(const float* __restrict__ thA, const float* __restrict__ thB,
    const int* __restrict__ fin,
    const float* __restrict__ W3, const float* __restrict__ b3,
    const float* __restrict__ g3, const float* __restrict__ bt3,
    const float* __restrict__ W4, const float* __restrict__ b4,
    const float* __restrict__ g4, const float* __restrict__ bt4,
    float* __restrict__ out) {
  __shared__ float Hs[4 * TD_N];
  __shared__ float H3[4 * TD_N];
  __shared__ float red[4][4][2];
  int tid = threadIdx.x;
  int r0 = blockIdx.x * 4;
  int j = tid;
  for (int i = tid; i < 4 * TD_N; i += 256) {
    int r = i >> 8, col = i & 255;
    int row = r0 + r;
    const float* src = (fin[row] ? thB : thA) + (size_t)row * TD_N + col;
    float v = __hip_atomic_load(src, __ATOMIC_RELAXED, __HIP_MEMORY_SCOPE_AGENT);
    Hs[i] = fmaxf(v, 0.0f);
  }
  __syncthreads();  // all reads of own rows complete before any write below
  float z[4] = {0, 0, 0, 0};
  {
    const float4* S4 = (const float4*)Hs;
    for (int k4 = 0; k4 < 64; k4++) {
      float w0 = W3[(k4 * 4 + 0) * TD_N + j];
      float w1 = W3[(k4 * 4 + 1) * TD_N + j];
      float w2 = W3[(k4 * 4 + 2) * TD_N + j];
      float w3v = W3[(k4 * 4 + 3) * TD_N + j];
#pragma unroll
      for (int r = 0; r < 4; r++) {
        float4 sv = S4[r * 64 + k4];
        z[r] += sv.x * w0 + sv.y * w1 + sv.z * w2 + sv.w * w3v;
      }
    }
  }
  for (int r = 0; r < 4; r++) z[r] += b3[j];
  int w = tid >> 6, lane = tid & 63;
  for (int r = 0; r < 4; r++) {
    float v = z[r], v2 = z[r] * z[r];
    for (int off = 32; off; off >>= 1) { v += __shfl_down(v, off); v2 += __shfl_down(v2, off); }
    if (lane == 0) { red[r][w][0] = v; red[r][w][1] = v2; }
  }
  __syncthreads();
  for (int r = 0; r < 4; r++) {
    float sm = red[r][0][0] + red[r][1][0] + red[r][2][0] + red[r][3][0];
    float sq = red[r][0][1] + red[r][1][1] + red[r][2][1] + red[r][3][1];
    float mean = sm * (1.0f / TD_N);
    float var = sq * (1.0f / TD_N) - mean * mean;
    float rs = 1.0f / sqrtf(var + 1e-5f);
    H3[r * TD_N + j] = (z[r] - mean) * rs * g3[j] + bt3[j];
  }
  __syncthreads();
  float z2a[4] = {0, 0, 0, 0};
  {
    const float4* S4 = (const float4*)H3;
    for (int k4 = 0; k4 < 64; k4++) {
      float w0 = W4[(k4 * 4 + 0) * TD_N + j];
      float w1 = W4[(k4 * 4 + 1) * TD_N + j];
      float w2 = W4[(k4 * 4 + 2) * TD_N + j];
      float w3v = W4[(k4 * 4 + 3) * TD_N + j];
#pragma unroll
      for (int r = 0; r < 4; r++) {
        float4 sv = S4[r * 64 + k4];
        z2a[r] += sv.x * w0 + sv.y * w1 + sv.z * w2 + sv.w * w3v;
      }
    }
  }
  for (int r = 0; r < 4; r++) z2a[r] += b4[j];
  __syncthreads();
  for (int r = 0; r < 4; r++) {
    float v = z2a[r], v2 = z2a[r] * z2a[r];
    for (int off = 32; off; off >>= 1) { v += __shfl_down(v, off); v2 += __shfl_down(v2, off); }
    if (lane == 0) { red[r][w][0] = v; red[r][w][1] = v2; }
  }
  __syncthreads();
  for (int r = 0; r < 4; r++) {
    float sm = red[r][0][0] + red[r][1][0] + red[r][2][0] + red[r][3][0];
    float sq = red[r][0][1] + red[r][1][1] + red[r][2][1] + red[r][3][1];
    float mean = sm * (1.0f / TD_N);
    float var = sq * (1.0f / TD_N) - mean * mean;
    float rs = 1.0f / sqrtf(var + 1e-5f);
    float val = (z2a[r] - mean) * rs * g4[j] + bt4[j];
    out[(size_t)(r0 + r) * TD_N + j] = tanhf(val);
  }
}

extern "C" void kernel_launch(void* const* d_in, const int* in_sizes, int n_in,
                              void* d_out, int out_size, void* d_ws, size_t ws_size,
                              hipStream_t stream) {
  const float* obs = (const float*)d_in[0];
  const unsigned char* C = (const unsigned char*)d_in[1];
  const float* W1 = (const float*)d_in[2];  const float* b1 = (const float*)d_in[3];
  const float* g1 = (const float*)d_in[4];  const float* bt1 = (const float*)d_in[5];
  const float* W2 = (const float*)d_in[6];  const float* b2 = (const float*)d_in[7];
  const float* g2 = (const float*)d_in[8];  const float* bt2 = (const float*)d_in[9];
  const float* aW1 = (const float*)d_in[10]; const float* ab1 = (const float*)d_in[11];
  const float* aW2 = (const float*)d_in[12]; const float* ab2 = (const float*)d_in[13];
  const float* aW3 = (const float*)d_in[14]; const float* ab3 = (const float*)d_in[15];
  const float* Wih_f = (const float*)d_in[16]; const float* Whh_f = (const float*)d_in[17];
  const float* bih_f = (const float*)d_in[18]; const float* bhh_f = (const float*)d_in[19];
  const float* Wih_r = (const float*)d_in[20]; const float* Whh_r = (const float*)d_in[21];
  const float* bih_r = (const float*)d_in[22]; const float* bhh_r = (const float*)d_in[23];
  const float* W3 = (const float*)d_in[24]; const float* b3 = (const float*)d_in[25];
  const float* g3 = (const float*)d_in[26]; const float* bt3 = (const float*)d_in[27];
  const float* W4 = (const float*)d_in[28]; const float* b4 = (const float*)d_in[29];
  const float* g4 = (const float*)d_in[30]; const float* bt4 = (const float*)d_in[31];
  float* out = (float*)d_out;

  // Workspace layout (float offsets). t_buf overlaps thB (dead before k_scan).
  float* ws = (float*)d_ws;
  unsigned int* wfragf = (unsigned int*)ws;             // 65536 u32
  unsigned int* wfragr = (unsigned int*)(ws + 131072);  // 65536 u32
  unsigned int* whhpf = (unsigned int*)(ws + 262144);   // 32768 u32
  unsigned int* whhpr = (unsigned int*)(ws + 327680);   // 32768 u32
  float* bsumf = ws + 393216;         // 512
  float* bsumr = ws + 393728;         // 512
  float* thB   = ws + 394240;         // 262144 (parity-1 thoughts buffer)
  float* t_buf = ws + 394240;         // overlap: used only before k_prep/k_scan
  int* ibase   = (int*)(ws + 656384);
  int* membi   = ibase;               // 16384
  int* reqi    = ibase + 16384;       // 16384
  int* isin    = ibase + 32768;       // 1024
  int* flag    = ibase + 33792;       // 64
  int* fin     = ibase + 33856;       // 1024
  int* lstart  = ibase + 34880;       // 64 (nact)
  int* llist   = ibase + 34944;       // 1024
  int* verF    = ibase + 35968;       // 1024
  int* verB    = ibase + 36992;       // 1024
  size_t need = (size_t)(656384 + 38016 + 64) * 4;  // ~2.78 MB
  if (ws_size < need) return;  // diagnosable absmax-fail instead of a fault

  (void)in_sizes; (void)n_in; (void)out_size;

  float* thA = out;  // parity-0 thoughts buffer aliases d_out

  k_cdet<<<1, 64, 0, stream>>>(C, flag);
  k_actor1a<<<256, 256, 0, stream>>>(obs, W1, b1, g1, bt1, t_buf);
  k_actor1b<<<256, 256, 0, stream>>>(t_buf, W2, b2, g2, bt2, thA);
  k_att<<<256, 256, 0, stream>>>(thA, aW1, ab1, aW2, ab2, aW3, ab3, isin);
  k_memb<<<1024, 64, 0, stream>>>(C, flag, membi);
  k_req<<<1024, 256, 0, stream>>>(C, flag, membi, isin, reqi);
  k_prep<<<512, 256, 0, stream>>>(Wih_f, Wih_r, Whh_f, Whh_r, bih_f, bhh_f, bih_r, bhh_r,
                                  wfragf, wfragr, whhpf, whhpr, bsumf, bsumr, verF, verB);
  k_lvl<<<1, 64, 0, stream>>>(isin, membi, fin, lstart, llist);
  k_scan<<<NWGC, 512, 0, stream>>>(thA, thB, lstart, llist, membi, reqi, verF, verB,
                                   wfragf, wfragr, whhpf, whhpr, bsumf, bsumr);
  k_actor2<<<256, 256, 0, stream>>>(thA, thB, fin, W3, b3, g3, bt3, W4, b4, g4, bt4, out);
}